// Round 1
// baseline (2226.674 us; speedup 1.0000x reference)
//
#include <hip/hip_runtime.h>
#include <hip/hip_bf16.h>

#define N_NODES 20000
#define E_EDGES 320000
#define NTRAIN  200000

// ---------------------------------------------------------------------------
// Generic f32 LDS-tiled GEMM:  C = POST( PRE(A) @ W + bias )
// PRE:  0 = none, 1 = sigmoid(A), 2 = A + pos_emb[positions[row]]
// POST: 0 = none, 1 = leaky(0.01)
// BM=BN=64, BK=16, 256 threads, 4x4 per thread.
// ---------------------------------------------------------------------------
template<int PRE, int POST>
__global__ __launch_bounds__(256) void gemm_f32(
    const float* __restrict__ A, const float* __restrict__ W,
    const float* __restrict__ bias, float* __restrict__ C,
    int M, int K, int Nn,
    const int* __restrict__ positions, const float* __restrict__ pos_emb)
{
    __shared__ float As[16][68];   // pad 64->68 keeps float4 alignment, kills write conflicts
    __shared__ float Bs[16][64];

    const int t  = threadIdx.x;
    const int m0 = blockIdx.x * 64;
    const int n0 = blockIdx.y * 64;

    const int kl  = t & 15;   // A-load k
    const int ml  = t >> 4;   // A-load m base
    const int nl  = t & 63;   // B-load n
    const int kl2 = t >> 6;   // B-load k group
    const int tc  = t & 15;   // compute col group
    const int tr  = t >> 4;   // compute row group

    float acc[4][4] = {};

    for (int k0 = 0; k0 < K; k0 += 16) {
        #pragma unroll
        for (int i = 0; i < 4; i++) {
            int m   = ml + i * 16;
            int row = m0 + m;
            float v = 0.f;
            if (row < M) {
                v = A[(size_t)row * K + k0 + kl];
                if (PRE == 1) v = 1.f / (1.f + expf(-v));
                if (PRE == 2) v += pos_emb[(size_t)positions[row] * K + k0 + kl];
            }
            As[kl][m] = v;
        }
        #pragma unroll
        for (int i = 0; i < 4; i++) {
            int kk = kl2 * 4 + i;
            Bs[kk][nl] = W[(size_t)(k0 + kk) * Nn + n0 + nl];
        }
        __syncthreads();
        #pragma unroll
        for (int kk = 0; kk < 16; kk++) {
            float4 ra = *reinterpret_cast<const float4*>(&As[kk][tr * 4]);
            float4 rb = *reinterpret_cast<const float4*>(&Bs[kk][tc * 4]);
            float am[4] = {ra.x, ra.y, ra.z, ra.w};
            float bn[4] = {rb.x, rb.y, rb.z, rb.w};
            #pragma unroll
            for (int i = 0; i < 4; i++)
                #pragma unroll
                for (int j = 0; j < 4; j++)
                    acc[i][j] += am[i] * bn[j];
        }
        __syncthreads();
    }

    #pragma unroll
    for (int i = 0; i < 4; i++) {
        int row = m0 + tr * 4 + i;
        if (row >= M) continue;
        #pragma unroll
        for (int j = 0; j < 4; j++) {
            int col = n0 + tc * 4 + j;
            float v = acc[i][j] + (bias ? bias[col] : 0.f);
            if (POST == 1) v = (v >= 0.f) ? v : 0.01f * v;
            C[(size_t)row * Nn + col] = v;
        }
    }
}

// ---------------------------------------------------------------------------
// Degree: deg = 1 + indegree(dst)
// ---------------------------------------------------------------------------
__global__ void deg_init(float* __restrict__ deg)
{
    int i = blockIdx.x * 256 + threadIdx.x;
    if (i < N_NODES) deg[i] = 1.0f;
}

__global__ void deg_acc(float* __restrict__ deg, const int* __restrict__ dst)
{
    int e = blockIdx.x * 256 + threadIdx.x;
    int stride = gridDim.x * 256;
    for (; e < E_EDGES; e += stride)
        atomicAdd(&deg[dst[e]], 1.0f);
}

// ---------------------------------------------------------------------------
// GCN self-term init: OUT = H * (1/deg) + b   (for both GCNs at once)
// grid = N_NODES blocks, 256 threads (one feature each)
// ---------------------------------------------------------------------------
__global__ __launch_bounds__(256) void gcn_combine(
    const float* __restrict__ H1, const float* __restrict__ H2,
    const float* __restrict__ deg,
    const float* __restrict__ b1, const float* __restrict__ b2,
    float* __restrict__ O1, float* __restrict__ O2)
{
    int i = blockIdx.x;
    int f = threadIdx.x;
    size_t idx = (size_t)i * 256 + f;
    float di2 = 1.0f / deg[i];
    O1[idx] = H1[idx] * di2 + b1[f];
    O2[idx] = H2[idx] * di2 + b2[f];
}

// ---------------------------------------------------------------------------
// Edge scatter: OUT[dst] += H[src] * (dinv[src]*dinv[dst])   (both GCNs)
// grid-stride over edges; block = 256 threads = 256 features
// ---------------------------------------------------------------------------
__global__ __launch_bounds__(256) void scatter_edges(
    const float* __restrict__ H1, const float* __restrict__ H2,
    const float* __restrict__ deg,
    const int* __restrict__ src, const int* __restrict__ dst,
    float* __restrict__ O1, float* __restrict__ O2)
{
    int f = threadIdx.x;
    for (int e = blockIdx.x; e < E_EDGES; e += gridDim.x) {
        int s = src[e];
        int d = dst[e];
        float coef = 1.0f / (sqrtf(deg[s]) * sqrtf(deg[d]));
        size_t si = (size_t)s * 256 + f;
        size_t di = (size_t)d * 256 + f;
        atomicAdd(&O1[di], H1[si] * coef);
        atomicAdd(&O2[di], H2[si] * coef);
    }
}

// ---------------------------------------------------------------------------
// Zero helper
// ---------------------------------------------------------------------------
__global__ void zero_kernel(float* __restrict__ p, int n)
{
    int i = blockIdx.x * 256 + threadIdx.x;
    if (i < n) p[i] = 0.f;
}

// ---------------------------------------------------------------------------
// kc = Ek @ k, vc = Ev @ v  (256 x 20000) @ (20000 x 128) with split-K atomics
// grid = (8 c-tiles, 8 K-splits, 2 matrices), block = 256
// ---------------------------------------------------------------------------
__global__ __launch_bounds__(256) void kcvc_kernel(
    const float* __restrict__ Ek, const float* __restrict__ Ev,
    const float* __restrict__ kin, const float* __restrict__ vin,
    float* __restrict__ kc, float* __restrict__ vc)
{
    const float* Emat = blockIdx.z ? Ev  : Ek;
    const float* X    = blockIdx.z ? vin : kin;
    float*       out  = blockIdx.z ? vc  : kc;

    const int c0 = blockIdx.x * 32;
    const int CH = (N_NODES + 7) / 8;            // 2500
    const int nStart = blockIdx.y * CH;
    const int nEnd   = min(nStart + CH, N_NODES);

    __shared__ float Xs[64][128];
    __shared__ float Es[32][64];

    const int t  = threadIdx.x;
    const int d  = t & 127;
    const int ch = t >> 7;    // 0..1
    float acc[16] = {};

    for (int nb = nStart; nb < nEnd; nb += 64) {
        #pragma unroll
        for (int i = 0; i < 32; i++) {
            int nl = (t >> 7) + i * 2;
            int n  = nb + nl;
            Xs[nl][d] = (n < nEnd) ? X[(size_t)n * 128 + d] : 0.f;
        }
        #pragma unroll
        for (int i = 0; i < 8; i++) {
            int cl = (t >> 6) + i * 4;
            int nn = t & 63;
            int n  = nb + nn;
            Es[cl][nn] = (n < nEnd) ? Emat[(size_t)(c0 + cl) * N_NODES + n] : 0.f;
        }
        __syncthreads();
        #pragma unroll 4
        for (int nn = 0; nn < 64; nn++) {
            float xv = Xs[nn][d];
            #pragma unroll
            for (int ci = 0; ci < 16; ci++)
                acc[ci] += Es[ch * 16 + ci][nn] * xv;
        }
        __syncthreads();
    }

    #pragma unroll
    for (int ci = 0; ci < 16; ci++)
        atomicAdd(&out[(size_t)(c0 + ch * 16 + ci) * 128 + d], acc[ci]);
}

// ---------------------------------------------------------------------------
// Fused attention: per node (one 64-lane wave), all 8 heads.
// scores[h,n,c] = dot(q[n,h,:], kc[c,h,:]) / 4 ; softmax over c (256);
// out[n,h,d] = sum_c w[c] * vc[c,h,d]
// ---------------------------------------------------------------------------
__global__ __launch_bounds__(64) void attn_kernel(
    const float* __restrict__ q, const float* __restrict__ kc,
    const float* __restrict__ vc, float* __restrict__ outp)
{
    const int n    = blockIdx.x;
    const int lane = threadIdx.x;

    __shared__ float q_s[128];
    __shared__ float w_s[256];

    q_s[lane]      = q[(size_t)n * 128 + lane];
    q_s[64 + lane] = q[(size_t)n * 128 + 64 + lane];
    __syncthreads();

    for (int h = 0; h < 8; h++) {
        float s[4];
        float m = -1e30f;
        #pragma unroll
        for (int ci = 0; ci < 4; ci++) {
            int c = lane * 4 + ci;
            const float* kr = &kc[(size_t)c * 128 + h * 16];
            const float* qr = &q_s[h * 16];
            float a = 0.f;
            #pragma unroll
            for (int d = 0; d < 16; d++) a += qr[d] * kr[d];
            s[ci] = a * 0.25f;
            m = fmaxf(m, s[ci]);
        }
        #pragma unroll
        for (int off = 32; off > 0; off >>= 1)
            m = fmaxf(m, __shfl_xor(m, off));
        float sum = 0.f;
        #pragma unroll
        for (int ci = 0; ci < 4; ci++) {
            s[ci] = expf(s[ci] - m);
            sum += s[ci];
        }
        #pragma unroll
        for (int off = 32; off > 0; off >>= 1)
            sum += __shfl_xor(sum, off);
        float inv = 1.0f / sum;

        __syncthreads();   // protect w_s against previous iteration's readers
        #pragma unroll
        for (int ci = 0; ci < 4; ci++)
            w_s[lane * 4 + ci] = s[ci] * inv;
        __syncthreads();

        const int d  = lane & 15;
        const int q4 = lane >> 4;
        float a = 0.f;
        #pragma unroll 4
        for (int i = 0; i < 64; i++) {
            int c = q4 * 64 + i;
            a += w_s[c] * vc[(size_t)c * 128 + h * 16 + d];
        }
        a += __shfl_xor(a, 16);
        a += __shfl_xor(a, 32);
        if (lane < 16)
            outp[(size_t)n * 128 + h * 16 + d] = a;
    }
}

// ---------------------------------------------------------------------------
// Cosine similarity over train pairs: one wave per pair, lane = feature (64)
// ---------------------------------------------------------------------------
__global__ __launch_bounds__(256) void cosine_kernel(
    const float* __restrict__ tfa, const float* __restrict__ tga,
    const int* __restrict__ ts, float* __restrict__ out)
{
    const int w    = threadIdx.x >> 6;
    const int lane = threadIdx.x & 63;
    const int t    = blockIdx.x * 4 + w;
    if (t >= NTRAIN) return;

    int i = ts[2 * t];
    int j = ts[2 * t + 1];
    float a = tfa[(size_t)i * 64 + lane];
    float b = tga[(size_t)j * 64 + lane];
    float da = a * b, na = a * a, nb = b * b;
    #pragma unroll
    for (int off = 32; off > 0; off >>= 1) {
        da += __shfl_xor(da, off);
        na += __shfl_xor(na, off);
        nb += __shfl_xor(nb, off);
    }
    if (lane == 0)
        out[t] = da / fmaxf(sqrtf(na) * sqrtf(nb), 1e-8f);
}

// ---------------------------------------------------------------------------
extern "C" void kernel_launch(void* const* d_in, const int* in_sizes, int n_in,
                              void* d_out, int out_size, void* d_ws, size_t ws_size,
                              hipStream_t stream)
{
    const int*   ts    = (const int*)  d_in[1];
    const float* X     = (const float*)d_in[2];   // data_feature
    const int*   adj   = (const int*)  d_in[3];
    const int*   pos   = (const int*)  d_in[4];
    const float* gcn_W = (const float*)d_in[5];
    const float* gcn_b = (const float*)d_in[6];
    const float* gA2_W = (const float*)d_in[7];
    const float* gA2_b = (const float*)d_in[8];
    const float* lin_W = (const float*)d_in[9];
    const float* lin_b = (const float*)d_in[10];
    const float* tf_W  = (const float*)d_in[11];
    const float* tf_b  = (const float*)d_in[12];
    const float* tg_W  = (const float*)d_in[13];
    const float* tg_b  = (const float*)d_in[14];
    const float* Wq    = (const float*)d_in[15];
    const float* bq    = (const float*)d_in[16];
    const float* Wk    = (const float*)d_in[17];
    const float* bk    = (const float*)d_in[18];
    const float* Wv    = (const float*)d_in[19];
    const float* bv    = (const float*)d_in[20];
    const float* Wo    = (const float*)d_in[21];
    const float* bo    = (const float*)d_in[22];
    const float* Ek    = (const float*)d_in[23];
    const float* Ev    = (const float*)d_in[24];
    const float* pemb  = (const float*)d_in[25];
    const float* tfaW  = (const float*)d_in[26];
    const float* tfab  = (const float*)d_in[27];
    const float* tgaW  = (const float*)d_in[28];
    const float* tgab  = (const float*)d_in[29];

    const int* src = adj;
    const int* dst = adj + E_EDGES;

    // ---- workspace layout (floats) ----
    float* ws  = (float*)d_ws;
    float* H1  = ws;                 // 20000*256
    float* H2  = H1 + 5120000;       // 20000*256
    float* O1  = H2 + 5120000;       // 20000*256
    float* O2  = O1 + 5120000;       // 20000*256
    float* deg = O2 + 5120000;       // 20000
    float* kc  = deg + 20000;        // 256*128
    float* vc  = kc + 32768;         // 256*128
    // aliases over dead buffers:
    float* xg   = H1;                // N*128  (after H1 dead)
    float* tfe  = H1 + 2560000;      // N*128
    float* tge  = H2;                // N*128
    float* qb   = H2 + 2560000;      // N*128
    float* kb   = O1;                // N*128  (after O1 dead)
    float* vb   = O1 + 2560000;      // N*128
    float* attn = O2;                // N*128  (after O2 dead)
    float* xf   = O2 + 2560000;      // N*128
    float* tfa  = H1;                // N*64   (after xg dead)
    float* tga  = H1 + 1280000;      // N*64

    dim3 blk(256);
    const int MB = (N_NODES + 63) / 64;   // 313

    // 1-2. H1 = X @ gcn_W ; H2 = X @ gcnA2_W   (no bias yet)
    gemm_f32<0,0><<<dim3(MB,4), blk, 0, stream>>>(X, gcn_W, nullptr, H1, N_NODES, 512, 256, nullptr, nullptr);
    gemm_f32<0,0><<<dim3(MB,4), blk, 0, stream>>>(X, gA2_W, nullptr, H2, N_NODES, 512, 256, nullptr, nullptr);

    // 3. degrees
    deg_init<<<(N_NODES + 255) / 256, blk, 0, stream>>>(deg);
    deg_acc<<<1250, blk, 0, stream>>>(deg, dst);

    // 4. self term + bias
    gcn_combine<<<N_NODES, blk, 0, stream>>>(H1, H2, deg, gcn_b, gA2_b, O1, O2);

    // 5. edge aggregation
    scatter_edges<<<20480, blk, 0, stream>>>(H1, H2, deg, src, dst, O1, O2);

    // 6. x_g = leaky(sigmoid(O1) @ lin_W + lin_b)
    gemm_f32<1,1><<<dim3(MB,2), blk, 0, stream>>>(O1, lin_W, lin_b, xg, N_NODES, 256, 128, nullptr, nullptr);
    // 7. tf_embed / target_embed = leaky(O2 @ W + b)
    gemm_f32<0,1><<<dim3(MB,2), blk, 0, stream>>>(O2, tf_W, tf_b, tfe, N_NODES, 256, 128, nullptr, nullptr);
    gemm_f32<0,1><<<dim3(MB,2), blk, 0, stream>>>(O2, tg_W, tg_b, tge, N_NODES, 256, 128, nullptr, nullptr);

    // 8. q = (xg+pe) @ Wq + bq ; k = (tf+pe) @ Wk + bk ; v = tg @ Wv + bv
    gemm_f32<2,0><<<dim3(MB,2), blk, 0, stream>>>(xg,  Wq, bq, qb, N_NODES, 128, 128, pos, pemb);
    gemm_f32<2,0><<<dim3(MB,2), blk, 0, stream>>>(tfe, Wk, bk, kb, N_NODES, 128, 128, pos, pemb);
    gemm_f32<0,0><<<dim3(MB,2), blk, 0, stream>>>(tge, Wv, bv, vb, N_NODES, 128, 128, nullptr, nullptr);

    // 9. kc/vc  (zero then split-K accumulate)
    zero_kernel<<<256, blk, 0, stream>>>(kc, 65536);   // kc and vc are contiguous
    kcvc_kernel<<<dim3(8, 8, 2), blk, 0, stream>>>(Ek, Ev, kb, vb, kc, vc);

    // 10. attention
    attn_kernel<<<N_NODES, 64, 0, stream>>>(qb, kc, vc, attn);

    // 11. x_f = attn @ Wo + bo
    gemm_f32<0,0><<<dim3(MB,2), blk, 0, stream>>>(attn, Wo, bo, xf, N_NODES, 128, 128, nullptr, nullptr);

    // 12. tfa / tga = leaky(x_f @ W + b)
    gemm_f32<0,1><<<dim3(MB,1), blk, 0, stream>>>(xf, tfaW, tfab, tfa, N_NODES, 128, 64, nullptr, nullptr);
    gemm_f32<0,1><<<dim3(MB,1), blk, 0, stream>>>(xf, tgaW, tgab, tga, N_NODES, 128, 64, nullptr, nullptr);

    // 13. cosine similarity
    cosine_kernel<<<NTRAIN / 4, blk, 0, stream>>>(tfa, tga, ts, (float*)d_out);
}

// Round 3
// 2085.001 us; speedup vs baseline: 1.0679x; 1.0679x over previous
//
#include <hip/hip_runtime.h>
#include <hip/hip_bf16.h>

#define N_NODES 20000
#define E_EDGES 320000
#define NTRAIN  200000
#define KC_SPLITS 128

// ---------------------------------------------------------------------------
// f32 LDS-tiled GEMM, BM=64 BN=64, 4x4/thread (used for N=64 outputs)
// PRE: 0 none, 1 sigmoid, 2 +pos_emb[positions[row]] ; POST: 0 none, 1 leaky
// ---------------------------------------------------------------------------
template<int PRE, int POST>
__global__ __launch_bounds__(256) void gemm_f32(
    const float* __restrict__ A, const float* __restrict__ W,
    const float* __restrict__ bias, float* __restrict__ C,
    int M, int K, int Nn,
    const int* __restrict__ positions, const float* __restrict__ pos_emb)
{
    __shared__ float As[16][68];
    __shared__ float Bs[16][64];

    const int t  = threadIdx.x;
    const int m0 = blockIdx.x * 64;
    const int n0 = blockIdx.y * 64;

    const int kl  = t & 15;
    const int ml  = t >> 4;
    const int nl  = t & 63;
    const int kl2 = t >> 6;
    const int tc  = t & 15;
    const int tr  = t >> 4;

    float acc[4][4] = {};

    for (int k0 = 0; k0 < K; k0 += 16) {
        #pragma unroll
        for (int i = 0; i < 4; i++) {
            int row = m0 + ml + i * 16;
            float v = 0.f;
            if (row < M) {
                v = A[(size_t)row * K + k0 + kl];
                if (PRE == 1) v = 1.f / (1.f + expf(-v));
                if (PRE == 2) v += pos_emb[(size_t)positions[row] * K + k0 + kl];
            }
            As[kl][ml + i * 16] = v;
        }
        #pragma unroll
        for (int i = 0; i < 4; i++) {
            int kk = kl2 * 4 + i;
            Bs[kk][nl] = W[(size_t)(k0 + kk) * Nn + n0 + nl];
        }
        __syncthreads();
        #pragma unroll
        for (int kk = 0; kk < 16; kk++) {
            float4 ra = *reinterpret_cast<const float4*>(&As[kk][tr * 4]);
            float4 rb = *reinterpret_cast<const float4*>(&Bs[kk][tc * 4]);
            float am[4] = {ra.x, ra.y, ra.z, ra.w};
            float bn[4] = {rb.x, rb.y, rb.z, rb.w};
            #pragma unroll
            for (int i = 0; i < 4; i++)
                #pragma unroll
                for (int j = 0; j < 4; j++)
                    acc[i][j] += am[i] * bn[j];
        }
        __syncthreads();
    }

    #pragma unroll
    for (int i = 0; i < 4; i++) {
        int row = m0 + tr * 4 + i;
        if (row >= M) continue;
        #pragma unroll
        for (int j = 0; j < 4; j++) {
            int col = n0 + tc * 4 + j;
            float v = acc[i][j] + (bias ? bias[col] : 0.f);
            if (POST == 1) v = (v >= 0.f) ? v : 0.01f * v;
            C[(size_t)row * Nn + col] = v;
        }
    }
}

// ---------------------------------------------------------------------------
// f32 LDS-tiled GEMM, BM=64 BN=128, 4x8/thread. Bs swizzled (+4*(col>>5)) so
// the 16-group float4 reads are 2-way on banks (free) instead of 4-way.
// ---------------------------------------------------------------------------
template<int PRE, int POST>
__global__ __launch_bounds__(256) void gemm_f32_n128(
    const float* __restrict__ A, const float* __restrict__ W,
    const float* __restrict__ bias, float* __restrict__ C,
    int M, int K, int Nn,
    const int* __restrict__ positions, const float* __restrict__ pos_emb)
{
    __shared__ float As[16][68];
    __shared__ float Bs[16][144];   // phys col = n + 4*(n>>5)

    const int t  = threadIdx.x;
    const int m0 = blockIdx.x * 64;
    const int n0 = blockIdx.y * 128;

    const int kl = t & 15;    // A-load k
    const int ml = t >> 4;    // A-load m base
    const int nl = t & 127;   // B-load n
    const int kb = t >> 7;    // B-load k base

    const int tc = t & 15;    // col group (8 cols)
    const int tr = t >> 4;    // row group (4 rows)
    const int bPhys = tc * 8 + (tc >> 2) * 4;

    float acc[4][8] = {};

    for (int k0 = 0; k0 < K; k0 += 16) {
        #pragma unroll
        for (int i = 0; i < 4; i++) {
            int row = m0 + ml + i * 16;
            float v = 0.f;
            if (row < M) {
                v = A[(size_t)row * K + k0 + kl];
                if (PRE == 1) v = 1.f / (1.f + expf(-v));
                if (PRE == 2) v += pos_emb[(size_t)positions[row] * K + k0 + kl];
            }
            As[kl][ml + i * 16] = v;
        }
        {
            int pc = nl + (nl >> 5) * 4;
            #pragma unroll
            for (int i = 0; i < 8; i++) {
                int kk = kb + i * 2;
                Bs[kk][pc] = W[(size_t)(k0 + kk) * Nn + n0 + nl];
            }
        }
        __syncthreads();
        #pragma unroll
        for (int kk = 0; kk < 16; kk++) {
            float4 ra  = *reinterpret_cast<const float4*>(&As[kk][tr * 4]);
            float4 rb0 = *reinterpret_cast<const float4*>(&Bs[kk][bPhys]);
            float4 rb1 = *reinterpret_cast<const float4*>(&Bs[kk][bPhys + 4]);
            float am[4] = {ra.x, ra.y, ra.z, ra.w};
            float bn[8] = {rb0.x, rb0.y, rb0.z, rb0.w, rb1.x, rb1.y, rb1.z, rb1.w};
            #pragma unroll
            for (int i = 0; i < 4; i++)
                #pragma unroll
                for (int j = 0; j < 8; j++)
                    acc[i][j] += am[i] * bn[j];
        }
        __syncthreads();
    }

    #pragma unroll
    for (int i = 0; i < 4; i++) {
        int row = m0 + tr * 4 + i;
        if (row >= M) continue;
        float4 o0, o1;
        float* po0 = (float*)&o0;
        float* po1 = (float*)&o1;
        #pragma unroll
        for (int j = 0; j < 4; j++) {
            float v = acc[i][j] + (bias ? bias[n0 + tc * 8 + j] : 0.f);
            if (POST == 1) v = (v >= 0.f) ? v : 0.01f * v;
            po0[j] = v;
            float w = acc[i][j + 4] + (bias ? bias[n0 + tc * 8 + 4 + j] : 0.f);
            if (POST == 1) w = (w >= 0.f) ? w : 0.01f * w;
            po1[j] = w;
        }
        *reinterpret_cast<float4*>(&C[(size_t)row * Nn + n0 + tc * 8])     = o0;
        *reinterpret_cast<float4*>(&C[(size_t)row * Nn + n0 + tc * 8 + 4]) = o1;
    }
}

// ---------------------------------------------------------------------------
// Degree: deg = 1 + indegree(dst)
// ---------------------------------------------------------------------------
__global__ void deg_init(float* __restrict__ deg)
{
    int i = blockIdx.x * 256 + threadIdx.x;
    if (i < N_NODES) deg[i] = 1.0f;
}

__global__ void deg_acc(float* __restrict__ deg, const int* __restrict__ dst)
{
    int e = blockIdx.x * 256 + threadIdx.x;
    int stride = gridDim.x * 256;
    for (; e < E_EDGES; e += stride)
        atomicAdd(&deg[dst[e]], 1.0f);
}

// ---------------------------------------------------------------------------
// GCN self term: OUT = H * (1/deg) + b   (both GCNs)
// ---------------------------------------------------------------------------
__global__ __launch_bounds__(256) void gcn_combine(
    const float* __restrict__ H1, const float* __restrict__ H2,
    const float* __restrict__ deg,
    const float* __restrict__ b1, const float* __restrict__ b2,
    float* __restrict__ O1, float* __restrict__ O2)
{
    int i = blockIdx.x;
    int f = threadIdx.x;
    size_t idx = (size_t)i * 256 + f;
    float di2 = 1.0f / deg[i];
    O1[idx] = H1[idx] * di2 + b1[f];
    O2[idx] = H2[idx] * di2 + b2[f];
}

// ---------------------------------------------------------------------------
// Edge scatter: OUT[dst] += H[src] * (dinv[src]*dinv[dst])   (both GCNs)
// ---------------------------------------------------------------------------
__global__ __launch_bounds__(256) void scatter_edges(
    const float* __restrict__ H1, const float* __restrict__ H2,
    const float* __restrict__ deg,
    const int* __restrict__ src, const int* __restrict__ dst,
    float* __restrict__ O1, float* __restrict__ O2)
{
    int f = threadIdx.x;
    for (int e = blockIdx.x; e < E_EDGES; e += gridDim.x) {
        int s = src[e];
        int d = dst[e];
        float coef = 1.0f / (sqrtf(deg[s]) * sqrtf(deg[d]));
        size_t si = (size_t)s * 256 + f;
        size_t di = (size_t)d * 256 + f;
        atomicAdd(&O1[di], H1[si] * coef);
        atomicAdd(&O2[di], H2[si] * coef);
    }
}

__global__ void zero_kernel(float* __restrict__ p, int n)
{
    int i = blockIdx.x * 256 + threadIdx.x;
    if (i < n) p[i] = 0.f;
}

// ---------------------------------------------------------------------------
// kc = Ek @ k, vc = Ev @ v : (256 x 20000) @ (20000 x 128), split-K atomics.
// grid = (2 c-tiles, KC_SPLITS, 2 matrices), block = 256.
// Both operands staged transposed in LDS: Es[nn][c], Xs[nn][d], phys col =
// col + 4*(col>>5) swizzle -> float4 reads are 2-way on banks (free).
// Each thread: 8c x 8d register tile -> 4 ds_read_b128 per 64 FMA.
// per-split chunk = 160 (multiple of 32) so all staged float4 loads stay
// 16B-aligned; splits past ceil(20000/160)=125 see an empty range.
// ---------------------------------------------------------------------------
__global__ __launch_bounds__(256) void kcvc_kernel(
    const float* __restrict__ Ek, const float* __restrict__ Ev,
    const float* __restrict__ kin, const float* __restrict__ vin,
    float* __restrict__ kc, float* __restrict__ vc)
{
    const float* E = blockIdx.z ? Ev  : Ek;
    const float* X = blockIdx.z ? vin : kin;
    float*       out = blockIdx.z ? vc : kc;

    const int c0 = blockIdx.x * 128;
    const int per = 160;                         // multiple of 32: alignment!
    const int nStart = blockIdx.y * per;
    const int nEnd   = min(nStart + per, N_NODES);

    __shared__ float Es[32][144];
    __shared__ float Xs[32][144];

    const int t  = threadIdx.x;
    const int tc = t & 15;     // c-group: c_local = tc*8 .. +7
    const int td = t >> 4;     // d-group: d = td*8 .. +7
    const int ePhys = tc * 8 + (tc >> 2) * 4;
    const int xPhys = td * 8 + (td >> 2) * 4;

    float acc[8][8] = {};

    for (int nb = nStart; nb < nEnd; nb += 32) {
        const int nc = min(32, nEnd - nb);

        // stage E chunk transposed: thread owns c_local = t>>1, half the nn's
        {
            int cl  = t >> 1;
            int pc  = cl + (cl >> 5) * 4;
            int nnb = (t & 1) * 16;
            const float* srcp = &E[(size_t)(c0 + cl) * N_NODES + nb + nnb];
            if (nc == 32) {
                #pragma unroll
                for (int i = 0; i < 4; i++) {
                    float4 v = *reinterpret_cast<const float4*>(&srcp[i * 4]);
                    Es[nnb + i * 4 + 0][pc] = v.x;
                    Es[nnb + i * 4 + 1][pc] = v.y;
                    Es[nnb + i * 4 + 2][pc] = v.z;
                    Es[nnb + i * 4 + 3][pc] = v.w;
                }
            } else {
                for (int i = 0; i < 16; i++) {
                    int nn = nnb + i;
                    Es[nn][pc] = (nn < nc) ? srcp[i] : 0.f;
                }
            }
        }
        // stage X chunk: [nn][d], coalesced float4
        {
            #pragma unroll
            for (int i = 0; i < 4; i++) {
                int g  = t + i * 256;
                int nn = g >> 5;
                int d0 = (g & 31) * 4;
                int pd = d0 + (d0 >> 5) * 4;
                if (nn < nc) {
                    float4 v = *reinterpret_cast<const float4*>(&X[(size_t)(nb + nn) * 128 + d0]);
                    Xs[nn][pd + 0] = v.x; Xs[nn][pd + 1] = v.y;
                    Xs[nn][pd + 2] = v.z; Xs[nn][pd + 3] = v.w;
                } else {
                    Xs[nn][pd + 0] = 0.f; Xs[nn][pd + 1] = 0.f;
                    Xs[nn][pd + 2] = 0.f; Xs[nn][pd + 3] = 0.f;
                }
            }
        }
        __syncthreads();

        #pragma unroll 2
        for (int nn = 0; nn < 32; nn++) {
            float4 e0 = *reinterpret_cast<const float4*>(&Es[nn][ePhys]);
            float4 e1 = *reinterpret_cast<const float4*>(&Es[nn][ePhys + 4]);
            float4 x0 = *reinterpret_cast<const float4*>(&Xs[nn][xPhys]);
            float4 x1 = *reinterpret_cast<const float4*>(&Xs[nn][xPhys + 4]);
            float ev[8] = {e0.x, e0.y, e0.z, e0.w, e1.x, e1.y, e1.z, e1.w};
            float xv[8] = {x0.x, x0.y, x0.z, x0.w, x1.x, x1.y, x1.z, x1.w};
            #pragma unroll
            for (int ci = 0; ci < 8; ci++)
                #pragma unroll
                for (int dj = 0; dj < 8; dj++)
                    acc[ci][dj] += ev[ci] * xv[dj];
        }
        __syncthreads();
    }

    #pragma unroll
    for (int ci = 0; ci < 8; ci++) {
        int c = c0 + tc * 8 + ci;
        #pragma unroll
        for (int dj = 0; dj < 8; dj++)
            atomicAdd(&out[(size_t)c * 128 + td * 8 + dj], acc[ci][dj]);
    }
}

// ---------------------------------------------------------------------------
// Fused attention: one 64-lane wave per node, all 8 heads.
// ---------------------------------------------------------------------------
__global__ __launch_bounds__(64) void attn_kernel(
    const float* __restrict__ q, const float* __restrict__ kc,
    const float* __restrict__ vc, float* __restrict__ outp)
{
    const int n    = blockIdx.x;
    const int lane = threadIdx.x;

    __shared__ float q_s[128];
    __shared__ float w_s[256];

    q_s[lane]      = q[(size_t)n * 128 + lane];
    q_s[64 + lane] = q[(size_t)n * 128 + 64 + lane];
    __syncthreads();

    for (int h = 0; h < 8; h++) {
        float s[4];
        float m = -1e30f;
        #pragma unroll
        for (int ci = 0; ci < 4; ci++) {
            int c = lane * 4 + ci;
            const float* kr = &kc[(size_t)c * 128 + h * 16];
            const float* qr = &q_s[h * 16];
            float a = 0.f;
            #pragma unroll
            for (int d = 0; d < 16; d++) a += qr[d] * kr[d];
            s[ci] = a * 0.25f;
            m = fmaxf(m, s[ci]);
        }
        #pragma unroll
        for (int off = 32; off > 0; off >>= 1)
            m = fmaxf(m, __shfl_xor(m, off));
        float sum = 0.f;
        #pragma unroll
        for (int ci = 0; ci < 4; ci++) {
            s[ci] = expf(s[ci] - m);
            sum += s[ci];
        }
        #pragma unroll
        for (int off = 32; off > 0; off >>= 1)
            sum += __shfl_xor(sum, off);
        float inv = 1.0f / sum;

        __syncthreads();
        #pragma unroll
        for (int ci = 0; ci < 4; ci++)
            w_s[lane * 4 + ci] = s[ci] * inv;
        __syncthreads();

        const int d  = lane & 15;
        const int q4 = lane >> 4;
        float a = 0.f;
        #pragma unroll 4
        for (int i = 0; i < 64; i++) {
            int c = q4 * 64 + i;
            a += w_s[c] * vc[(size_t)c * 128 + h * 16 + d];
        }
        a += __shfl_xor(a, 16);
        a += __shfl_xor(a, 32);
        if (lane < 16)
            outp[(size_t)n * 128 + h * 16 + d] = a;
    }
}

// ---------------------------------------------------------------------------
// Cosine similarity: one wave per pair, 64 lanes = 64 features
// ---------------------------------------------------------------------------
__global__ __launch_bounds__(256) void cosine_kernel(
    const float* __restrict__ tfa, const float* __restrict__ tga,
    const int* __restrict__ ts, float* __restrict__ out)
{
    const int w    = threadIdx.x >> 6;
    const int lane = threadIdx.x & 63;
    const int t    = blockIdx.x * 4 + w;
    if (t >= NTRAIN) return;

    int i = ts[2 * t];
    int j = ts[2 * t + 1];
    float a = tfa[(size_t)i * 64 + lane];
    float b = tga[(size_t)j * 64 + lane];
    float da = a * b, na = a * a, nb = b * b;
    #pragma unroll
    for (int off = 32; off > 0; off >>= 1) {
        da += __shfl_xor(da, off);
        na += __shfl_xor(na, off);
        nb += __shfl_xor(nb, off);
    }
    if (lane == 0)
        out[t] = da / fmaxf(sqrtf(na) * sqrtf(nb), 1e-8f);
}

// ---------------------------------------------------------------------------
extern "C" void kernel_launch(void* const* d_in, const int* in_sizes, int n_in,
                              void* d_out, int out_size, void* d_ws, size_t ws_size,
                              hipStream_t stream)
{
    const int*   ts    = (const int*)  d_in[1];
    const float* X     = (const float*)d_in[2];
    const int*   adj   = (const int*)  d_in[3];
    const int*   pos   = (const int*)  d_in[4];
    const float* gcn_W = (const float*)d_in[5];
    const float* gcn_b = (const float*)d_in[6];
    const float* gA2_W = (const float*)d_in[7];
    const float* gA2_b = (const float*)d_in[8];
    const float* lin_W = (const float*)d_in[9];
    const float* lin_b = (const float*)d_in[10];
    const float* tf_W  = (const float*)d_in[11];
    const float* tf_b  = (const float*)d_in[12];
    const float* tg_W  = (const float*)d_in[13];
    const float* tg_b  = (const float*)d_in[14];
    const float* Wq    = (const float*)d_in[15];
    const float* bq    = (const float*)d_in[16];
    const float* Wk    = (const float*)d_in[17];
    const float* bk    = (const float*)d_in[18];
    const float* Wv    = (const float*)d_in[19];
    const float* bv    = (const float*)d_in[20];
    const float* Wo    = (const float*)d_in[21];
    const float* bo    = (const float*)d_in[22];
    const float* Ek    = (const float*)d_in[23];
    const float* Ev    = (const float*)d_in[24];
    const float* pemb  = (const float*)d_in[25];
    const float* tfaW  = (const float*)d_in[26];
    const float* tfab  = (const float*)d_in[27];
    const float* tgaW  = (const float*)d_in[28];
    const float* tgab  = (const float*)d_in[29];

    const int* src = adj;
    const int* dst = adj + E_EDGES;

    float* ws  = (float*)d_ws;
    float* H1  = ws;                 // 20000*256
    float* H2  = H1 + 5120000;
    float* O1  = H2 + 5120000;
    float* O2  = O1 + 5120000;
    float* deg = O2 + 5120000;       // 20000
    float* kc  = deg + 20000;        // 256*128
    float* vc  = kc + 32768;
    // aliases over dead buffers:
    float* xg   = H1;
    float* tfe  = H1 + 2560000;
    float* tge  = H2;
    float* qb   = H2 + 2560000;
    float* kb   = O1;
    float* vb   = O1 + 2560000;
    float* attn = O2;
    float* xf   = O2 + 2560000;
    float* tfa  = H1;
    float* tga  = H1 + 1280000;

    dim3 blk(256);
    const int MB = (N_NODES + 63) / 64;   // 313

    // 1-2. H1 = X @ gcn_W ; H2 = X @ gcnA2_W
    gemm_f32_n128<0,0><<<dim3(MB,2), blk, 0, stream>>>(X, gcn_W, nullptr, H1, N_NODES, 512, 256, nullptr, nullptr);
    gemm_f32_n128<0,0><<<dim3(MB,2), blk, 0, stream>>>(X, gA2_W, nullptr, H2, N_NODES, 512, 256, nullptr, nullptr);

    // 3. degrees
    deg_init<<<(N_NODES + 255) / 256, blk, 0, stream>>>(deg);
    deg_acc<<<1250, blk, 0, stream>>>(deg, dst);

    // 4. self term + bias
    gcn_combine<<<N_NODES, blk, 0, stream>>>(H1, H2, deg, gcn_b, gA2_b, O1, O2);

    // 5. edge aggregation
    scatter_edges<<<20480, blk, 0, stream>>>(H1, H2, deg, src, dst, O1, O2);

    // 6-7. projections to HIDDEN
    gemm_f32_n128<1,1><<<dim3(MB,1), blk, 0, stream>>>(O1, lin_W, lin_b, xg, N_NODES, 256, 128, nullptr, nullptr);
    gemm_f32_n128<0,1><<<dim3(MB,1), blk, 0, stream>>>(O2, tf_W, tf_b, tfe, N_NODES, 256, 128, nullptr, nullptr);
    gemm_f32_n128<0,1><<<dim3(MB,1), blk, 0, stream>>>(O2, tg_W, tg_b, tge, N_NODES, 256, 128, nullptr, nullptr);

    // 8. q / k / v
    gemm_f32_n128<2,0><<<dim3(MB,1), blk, 0, stream>>>(xg,  Wq, bq, qb, N_NODES, 128, 128, pos, pemb);
    gemm_f32_n128<2,0><<<dim3(MB,1), blk, 0, stream>>>(tfe, Wk, bk, kb, N_NODES, 128, 128, pos, pemb);
    gemm_f32_n128<0,0><<<dim3(MB,1), blk, 0, stream>>>(tge, Wv, bv, vb, N_NODES, 128, 128, nullptr, nullptr);

    // 9. kc/vc
    zero_kernel<<<256, blk, 0, stream>>>(kc, 65536);
    kcvc_kernel<<<dim3(2, KC_SPLITS, 2), blk, 0, stream>>>(Ek, Ev, kb, vb, kc, vc);

    // 10. attention
    attn_kernel<<<N_NODES, 64, 0, stream>>>(qb, kc, vc, attn);

    // 11. x_f = attn @ Wo + bo
    gemm_f32_n128<0,0><<<dim3(MB,1), blk, 0, stream>>>(attn, Wo, bo, xf, N_NODES, 128, 128, nullptr, nullptr);

    // 12. tfa / tga
    gemm_f32<0,1><<<dim3(MB,1), blk, 0, stream>>>(xf, tfaW, tfab, tfa, N_NODES, 128, 64, nullptr, nullptr);
    gemm_f32<0,1><<<dim3(MB,1), blk, 0, stream>>>(xf, tgaW, tgab, tga, N_NODES, 128, 64, nullptr, nullptr);

    // 13. cosine similarity
    cosine_kernel<<<NTRAIN / 4, blk, 0, stream>>>(tfa, tga, ts, (float*)d_out);
}

// Round 5
// 1721.581 us; speedup vs baseline: 1.2934x; 1.2111x over previous
//
#include <hip/hip_runtime.h>
#include <hip/hip_bf16.h>

#define N_NODES 20000
#define E_EDGES 320000
#define NTRAIN  200000
#define KC_SPLITS 128

// ---------------------------------------------------------------------------
// f32 LDS-tiled GEMM, BM=64 BN=64, 4x4/thread (used for N=64 outputs)
// PRE: 0 none, 1 sigmoid, 2 +pos_emb[positions[row]] ; POST: 0 none, 1 leaky
// ---------------------------------------------------------------------------
template<int PRE, int POST>
__global__ __launch_bounds__(256) void gemm_f32(
    const float* __restrict__ A, const float* __restrict__ W,
    const float* __restrict__ bias, float* __restrict__ C,
    int M, int K, int Nn,
    const int* __restrict__ positions, const float* __restrict__ pos_emb)
{
    __shared__ float As[16][68];
    __shared__ float Bs[16][64];

    const int t  = threadIdx.x;
    const int m0 = blockIdx.x * 64;
    const int n0 = blockIdx.y * 64;

    const int kl  = t & 15;
    const int ml  = t >> 4;
    const int nl  = t & 63;
    const int kl2 = t >> 6;
    const int tc  = t & 15;
    const int tr  = t >> 4;

    float acc[4][4] = {};

    for (int k0 = 0; k0 < K; k0 += 16) {
        #pragma unroll
        for (int i = 0; i < 4; i++) {
            int row = m0 + ml + i * 16;
            float v = 0.f;
            if (row < M) {
                v = A[(size_t)row * K + k0 + kl];
                if (PRE == 1) v = 1.f / (1.f + expf(-v));
                if (PRE == 2) v += pos_emb[(size_t)positions[row] * K + k0 + kl];
            }
            As[kl][ml + i * 16] = v;
        }
        #pragma unroll
        for (int i = 0; i < 4; i++) {
            int kk = kl2 * 4 + i;
            Bs[kk][nl] = W[(size_t)(k0 + kk) * Nn + n0 + nl];
        }
        __syncthreads();
        #pragma unroll
        for (int kk = 0; kk < 16; kk++) {
            float4 ra = *reinterpret_cast<const float4*>(&As[kk][tr * 4]);
            float4 rb = *reinterpret_cast<const float4*>(&Bs[kk][tc * 4]);
            float am[4] = {ra.x, ra.y, ra.z, ra.w};
            float bn[4] = {rb.x, rb.y, rb.z, rb.w};
            #pragma unroll
            for (int i = 0; i < 4; i++)
                #pragma unroll
                for (int j = 0; j < 4; j++)
                    acc[i][j] += am[i] * bn[j];
        }
        __syncthreads();
    }

    #pragma unroll
    for (int i = 0; i < 4; i++) {
        int row = m0 + tr * 4 + i;
        if (row >= M) continue;
        #pragma unroll
        for (int j = 0; j < 4; j++) {
            int col = n0 + tc * 4 + j;
            float v = acc[i][j] + (bias ? bias[col] : 0.f);
            if (POST == 1) v = (v >= 0.f) ? v : 0.01f * v;
            C[(size_t)row * Nn + col] = v;
        }
    }
}

// ---------------------------------------------------------------------------
// f32 LDS-tiled GEMM, BM=64 BN=128, 4x8/thread. Bs swizzled (+4*(col>>5)) so
// the 16-group float4 reads are 2-way on banks (free) instead of 4-way.
// ---------------------------------------------------------------------------
template<int PRE, int POST>
__global__ __launch_bounds__(256) void gemm_f32_n128(
    const float* __restrict__ A, const float* __restrict__ W,
    const float* __restrict__ bias, float* __restrict__ C,
    int M, int K, int Nn,
    const int* __restrict__ positions, const float* __restrict__ pos_emb)
{
    __shared__ float As[16][68];
    __shared__ float Bs[16][144];   // phys col = n + 4*(n>>5)

    const int t  = threadIdx.x;
    const int m0 = blockIdx.x * 64;
    const int n0 = blockIdx.y * 128;

    const int kl = t & 15;    // A-load k
    const int ml = t >> 4;    // A-load m base
    const int nl = t & 127;   // B-load n
    const int kb = t >> 7;    // B-load k base

    const int tc = t & 15;    // col group (8 cols)
    const int tr = t >> 4;    // row group (4 rows)
    const int bPhys = tc * 8 + (tc >> 2) * 4;

    float acc[4][8] = {};

    for (int k0 = 0; k0 < K; k0 += 16) {
        #pragma unroll
        for (int i = 0; i < 4; i++) {
            int row = m0 + ml + i * 16;
            float v = 0.f;
            if (row < M) {
                v = A[(size_t)row * K + k0 + kl];
                if (PRE == 1) v = 1.f / (1.f + expf(-v));
                if (PRE == 2) v += pos_emb[(size_t)positions[row] * K + k0 + kl];
            }
            As[kl][ml + i * 16] = v;
        }
        {
            int pc = nl + (nl >> 5) * 4;
            #pragma unroll
            for (int i = 0; i < 8; i++) {
                int kk = kb + i * 2;
                Bs[kk][pc] = W[(size_t)(k0 + kk) * Nn + n0 + nl];
            }
        }
        __syncthreads();
        #pragma unroll
        for (int kk = 0; kk < 16; kk++) {
            float4 ra  = *reinterpret_cast<const float4*>(&As[kk][tr * 4]);
            float4 rb0 = *reinterpret_cast<const float4*>(&Bs[kk][bPhys]);
            float4 rb1 = *reinterpret_cast<const float4*>(&Bs[kk][bPhys + 4]);
            float am[4] = {ra.x, ra.y, ra.z, ra.w};
            float bn[8] = {rb0.x, rb0.y, rb0.z, rb0.w, rb1.x, rb1.y, rb1.z, rb1.w};
            #pragma unroll
            for (int i = 0; i < 4; i++)
                #pragma unroll
                for (int j = 0; j < 8; j++)
                    acc[i][j] += am[i] * bn[j];
        }
        __syncthreads();
    }

    #pragma unroll
    for (int i = 0; i < 4; i++) {
        int row = m0 + tr * 4 + i;
        if (row >= M) continue;
        float4 o0, o1;
        float* po0 = (float*)&o0;
        float* po1 = (float*)&o1;
        #pragma unroll
        for (int j = 0; j < 4; j++) {
            float v = acc[i][j] + (bias ? bias[n0 + tc * 8 + j] : 0.f);
            if (POST == 1) v = (v >= 0.f) ? v : 0.01f * v;
            po0[j] = v;
            float w = acc[i][j + 4] + (bias ? bias[n0 + tc * 8 + 4 + j] : 0.f);
            if (POST == 1) w = (w >= 0.f) ? w : 0.01f * w;
            po1[j] = w;
        }
        *reinterpret_cast<float4*>(&C[(size_t)row * Nn + n0 + tc * 8])     = o0;
        *reinterpret_cast<float4*>(&C[(size_t)row * Nn + n0 + tc * 8 + 4]) = o1;
    }
}

__global__ void zero_kernel(float* __restrict__ p, int n)
{
    int i = blockIdx.x * 256 + threadIdx.x;
    if (i < n) p[i] = 0.f;
}

// ---------------------------------------------------------------------------
// CSR build step 1: count[n] = indegree(n)  (count pre-zeroed)
// ---------------------------------------------------------------------------
__global__ void csr_count(const int* __restrict__ dst, int* __restrict__ count)
{
    int e = blockIdx.x * 256 + threadIdx.x;
    int stride = gridDim.x * 256;
    for (; e < E_EDGES; e += stride)
        atomicAdd(&count[dst[e]], 1);
}

// ---------------------------------------------------------------------------
// CSR build step 2: single-block exclusive scan of count -> rowptr, cursor.
// Also emits dinv[n] = rsqrt(1 + indegree) (the GCN degree normalizer).
// ---------------------------------------------------------------------------
__global__ __launch_bounds__(1024) void csr_scan(
    const int* __restrict__ count, int* __restrict__ rowptr,
    int* __restrict__ cursor, float* __restrict__ dinv)
{
    __shared__ int s[1024];
    const int t = threadIdx.x;
    int carry = 0;
    for (int base = 0; base < N_NODES; base += 1024) {
        int i = base + t;
        int v = (i < N_NODES) ? count[i] : 0;
        if (i < N_NODES) dinv[i] = rsqrtf(1.f + (float)v);
        s[t] = v;
        __syncthreads();
        for (int off = 1; off < 1024; off <<= 1) {
            int add = (t >= off) ? s[t - off] : 0;
            __syncthreads();
            s[t] += add;
            __syncthreads();
        }
        int incl  = s[t];
        int total = s[1023];
        if (i < N_NODES) {
            rowptr[i] = carry + incl - v;
            cursor[i] = carry + incl - v;
        }
        carry += total;
        __syncthreads();   // s reused next iteration
    }
    if (t == 0) rowptr[N_NODES] = carry;
}

// ---------------------------------------------------------------------------
// CSR build step 3: bucket edge sources by dst
// ---------------------------------------------------------------------------
__global__ void csr_fill(const int* __restrict__ src, const int* __restrict__ dst,
                         int* __restrict__ cursor, int* __restrict__ srcs)
{
    int e = blockIdx.x * 256 + threadIdx.x;
    int stride = gridDim.x * 256;
    for (; e < E_EDGES; e += stride) {
        int slot = atomicAdd(&cursor[dst[e]], 1);
        srcs[slot] = src[e];
    }
}

// ---------------------------------------------------------------------------
// GCN aggregation, gather-side (no float atomics):
// O[n] = sum_{s in in(n)} H[s]*dinv[s]*dinv[n] + H[n]*dinv[n]^2 + b
// One block per node, 256 threads = 256 features; both GCNs at once.
// srcs/dinv loads are wave-uniform -> scalar; row reads are coalesced 1KB.
// ---------------------------------------------------------------------------
__global__ __launch_bounds__(256) void gcn_aggregate(
    const float* __restrict__ H1, const float* __restrict__ H2,
    const float* __restrict__ dinv,
    const int* __restrict__ rowptr, const int* __restrict__ srcs,
    const float* __restrict__ b1, const float* __restrict__ b2,
    float* __restrict__ O1, float* __restrict__ O2)
{
    const int n = blockIdx.x;
    const int f = threadIdx.x;
    const float dn = dinv[n];
    const size_t nidx = (size_t)n * 256 + f;

    float a1 = H1[nidx] * dn * dn + b1[f];
    float a2 = H2[nidx] * dn * dn + b2[f];

    const int e0 = rowptr[n];
    const int e1 = rowptr[n + 1];
    for (int e = e0; e < e1; e++) {
        int s = srcs[e];
        float c = dinv[s] * dn;
        size_t si = (size_t)s * 256 + f;
        a1 += H1[si] * c;
        a2 += H2[si] * c;
    }
    O1[nidx] = a1;
    O2[nidx] = a2;
}

// ---------------------------------------------------------------------------
// kc = Ek @ k, vc = Ev @ v : (256 x 20000) @ (20000 x 128), split-K atomics.
// ---------------------------------------------------------------------------
__global__ __launch_bounds__(256) void kcvc_kernel(
    const float* __restrict__ Ek, const float* __restrict__ Ev,
    const float* __restrict__ kin, const float* __restrict__ vin,
    float* __restrict__ kc, float* __restrict__ vc)
{
    const float* E = blockIdx.z ? Ev  : Ek;
    const float* X = blockIdx.z ? vin : kin;
    float*       out = blockIdx.z ? vc : kc;

    const int c0 = blockIdx.x * 128;
    const int per = 160;                         // multiple of 32: alignment!
    const int nStart = blockIdx.y * per;
    const int nEnd   = min(nStart + per, N_NODES);

    __shared__ float Es[32][144];
    __shared__ float Xs[32][144];

    const int t  = threadIdx.x;
    const int tc = t & 15;
    const int td = t >> 4;
    const int ePhys = tc * 8 + (tc >> 2) * 4;
    const int xPhys = td * 8 + (td >> 2) * 4;

    float acc[8][8] = {};

    for (int nb = nStart; nb < nEnd; nb += 32) {
        const int nc = min(32, nEnd - nb);

        {
            int cl  = t >> 1;
            int pc  = cl + (cl >> 5) * 4;
            int nnb = (t & 1) * 16;
            const float* srcp = &E[(size_t)(c0 + cl) * N_NODES + nb + nnb];
            if (nc == 32) {
                #pragma unroll
                for (int i = 0; i < 4; i++) {
                    float4 v = *reinterpret_cast<const float4*>(&srcp[i * 4]);
                    Es[nnb + i * 4 + 0][pc] = v.x;
                    Es[nnb + i * 4 + 1][pc] = v.y;
                    Es[nnb + i * 4 + 2][pc] = v.z;
                    Es[nnb + i * 4 + 3][pc] = v.w;
                }
            } else {
                for (int i = 0; i < 16; i++) {
                    int nn = nnb + i;
                    Es[nn][pc] = (nn < nc) ? srcp[i] : 0.f;
                }
            }
        }
        {
            #pragma unroll
            for (int i = 0; i < 4; i++) {
                int g  = t + i * 256;
                int nn = g >> 5;
                int d0 = (g & 31) * 4;
                int pd = d0 + (d0 >> 5) * 4;
                if (nn < nc) {
                    float4 v = *reinterpret_cast<const float4*>(&X[(size_t)(nb + nn) * 128 + d0]);
                    Xs[nn][pd + 0] = v.x; Xs[nn][pd + 1] = v.y;
                    Xs[nn][pd + 2] = v.z; Xs[nn][pd + 3] = v.w;
                } else {
                    Xs[nn][pd + 0] = 0.f; Xs[nn][pd + 1] = 0.f;
                    Xs[nn][pd + 2] = 0.f; Xs[nn][pd + 3] = 0.f;
                }
            }
        }
        __syncthreads();

        #pragma unroll 2
        for (int nn = 0; nn < 32; nn++) {
            float4 e0 = *reinterpret_cast<const float4*>(&Es[nn][ePhys]);
            float4 e1 = *reinterpret_cast<const float4*>(&Es[nn][ePhys + 4]);
            float4 x0 = *reinterpret_cast<const float4*>(&Xs[nn][xPhys]);
            float4 x1 = *reinterpret_cast<const float4*>(&Xs[nn][xPhys + 4]);
            float ev[8] = {e0.x, e0.y, e0.z, e0.w, e1.x, e1.y, e1.z, e1.w};
            float xv[8] = {x0.x, x0.y, x0.z, x0.w, x1.x, x1.y, x1.z, x1.w};
            #pragma unroll
            for (int ci = 0; ci < 8; ci++)
                #pragma unroll
                for (int dj = 0; dj < 8; dj++)
                    acc[ci][dj] += ev[ci] * xv[dj];
        }
        __syncthreads();
    }

    #pragma unroll
    for (int ci = 0; ci < 8; ci++) {
        int c = c0 + tc * 8 + ci;
        #pragma unroll
        for (int dj = 0; dj < 8; dj++)
            atomicAdd(&out[(size_t)c * 128 + td * 8 + dj], acc[ci][dj]);
    }
}

// ---------------------------------------------------------------------------
// Fused attention: one 64-lane wave per node, all 8 heads.
// ---------------------------------------------------------------------------
__global__ __launch_bounds__(64) void attn_kernel(
    const float* __restrict__ q, const float* __restrict__ kc,
    const float* __restrict__ vc, float* __restrict__ outp)
{
    const int n    = blockIdx.x;
    const int lane = threadIdx.x;

    __shared__ float q_s[128];
    __shared__ float w_s[256];

    q_s[lane]      = q[(size_t)n * 128 + lane];
    q_s[64 + lane] = q[(size_t)n * 128 + 64 + lane];
    __syncthreads();

    for (int h = 0; h < 8; h++) {
        float s[4];
        float m = -1e30f;
        #pragma unroll
        for (int ci = 0; ci < 4; ci++) {
            int c = lane * 4 + ci;
            const float* kr = &kc[(size_t)c * 128 + h * 16];
            const float* qr = &q_s[h * 16];
            float a = 0.f;
            #pragma unroll
            for (int d = 0; d < 16; d++) a += qr[d] * kr[d];
            s[ci] = a * 0.25f;
            m = fmaxf(m, s[ci]);
        }
        #pragma unroll
        for (int off = 32; off > 0; off >>= 1)
            m = fmaxf(m, __shfl_xor(m, off));
        float sum = 0.f;
        #pragma unroll
        for (int ci = 0; ci < 4; ci++) {
            s[ci] = expf(s[ci] - m);
            sum += s[ci];
        }
        #pragma unroll
        for (int off = 32; off > 0; off >>= 1)
            sum += __shfl_xor(sum, off);
        float inv = 1.0f / sum;

        __syncthreads();
        #pragma unroll
        for (int ci = 0; ci < 4; ci++)
            w_s[lane * 4 + ci] = s[ci] * inv;
        __syncthreads();

        const int d  = lane & 15;
        const int q4 = lane >> 4;
        float a = 0.f;
        #pragma unroll 4
        for (int i = 0; i < 64; i++) {
            int c = q4 * 64 + i;
            a += w_s[c] * vc[(size_t)c * 128 + h * 16 + d];
        }
        a += __shfl_xor(a, 16);
        a += __shfl_xor(a, 32);
        if (lane < 16)
            outp[(size_t)n * 128 + h * 16 + d] = a;
    }
}

// ---------------------------------------------------------------------------
// Cosine similarity: one wave per pair, 64 lanes = 64 features
// ---------------------------------------------------------------------------
__global__ __launch_bounds__(256) void cosine_kernel(
    const float* __restrict__ tfa, const float* __restrict__ tga,
    const int* __restrict__ ts, float* __restrict__ out)
{
    const int w    = threadIdx.x >> 6;
    const int lane = threadIdx.x & 63;
    const int t    = blockIdx.x * 4 + w;
    if (t >= NTRAIN) return;

    int i = ts[2 * t];
    int j = ts[2 * t + 1];
    float a = tfa[(size_t)i * 64 + lane];
    float b = tga[(size_t)j * 64 + lane];
    float da = a * b, na = a * a, nb = b * b;
    #pragma unroll
    for (int off = 32; off > 0; off >>= 1) {
        da += __shfl_xor(da, off);
        na += __shfl_xor(na, off);
        nb += __shfl_xor(nb, off);
    }
    if (lane == 0)
        out[t] = da / fmaxf(sqrtf(na) * sqrtf(nb), 1e-8f);
}

// ---------------------------------------------------------------------------
extern "C" void kernel_launch(void* const* d_in, const int* in_sizes, int n_in,
                              void* d_out, int out_size, void* d_ws, size_t ws_size,
                              hipStream_t stream)
{
    const int*   ts    = (const int*)  d_in[1];
    const float* X     = (const float*)d_in[2];
    const int*   adj   = (const int*)  d_in[3];
    const int*   pos   = (const int*)  d_in[4];
    const float* gcn_W = (const float*)d_in[5];
    const float* gcn_b = (const float*)d_in[6];
    const float* gA2_W = (const float*)d_in[7];
    const float* gA2_b = (const float*)d_in[8];
    const float* lin_W = (const float*)d_in[9];
    const float* lin_b = (const float*)d_in[10];
    const float* tf_W  = (const float*)d_in[11];
    const float* tf_b  = (const float*)d_in[12];
    const float* tg_W  = (const float*)d_in[13];
    const float* tg_b  = (const float*)d_in[14];
    const float* Wq    = (const float*)d_in[15];
    const float* bq    = (const float*)d_in[16];
    const float* Wk    = (const float*)d_in[17];
    const float* bk    = (const float*)d_in[18];
    const float* Wv    = (const float*)d_in[19];
    const float* bv    = (const float*)d_in[20];
    const float* Wo    = (const float*)d_in[21];
    const float* bo    = (const float*)d_in[22];
    const float* Ek    = (const float*)d_in[23];
    const float* Ev    = (const float*)d_in[24];
    const float* pemb  = (const float*)d_in[25];
    const float* tfaW  = (const float*)d_in[26];
    const float* tfab  = (const float*)d_in[27];
    const float* tgaW  = (const float*)d_in[28];
    const float* tgab  = (const float*)d_in[29];

    const int* src = adj;
    const int* dst = adj + E_EDGES;

    float* ws  = (float*)d_ws;
    float* H1  = ws;                 // 20000*256
    float* H2  = H1 + 5120000;
    float* O1  = H2 + 5120000;
    float* O2  = O1 + 5120000;
    float* dinv = O2 + 5120000;      // 20000
    float* kc  = dinv + 20000;       // 256*128
    float* vc  = kc + 32768;         // 256*128
    int*   count  = (int*)(vc + 32768);     // 20000
    int*   rowptr = count + 20000;          // 20001
    int*   cursor = rowptr + 20001;         // 20000
    int*   srcs   = cursor + 20000;         // 320000
    // aliases over dead buffers:
    float* xg   = H1;
    float* tfe  = H1 + 2560000;
    float* tge  = H2;
    float* qb   = H2 + 2560000;
    float* kb   = O1;
    float* vb   = O1 + 2560000;
    float* attn = O2;
    float* xf   = O2 + 2560000;
    float* tfa  = H1;
    float* tga  = H1 + 1280000;

    dim3 blk(256);
    const int MB = (N_NODES + 63) / 64;   // 313

    // 1-2. H1 = X @ gcn_W ; H2 = X @ gcnA2_W
    gemm_f32_n128<0,0><<<dim3(MB,2), blk, 0, stream>>>(X, gcn_W, nullptr, H1, N_NODES, 512, 256, nullptr, nullptr);
    gemm_f32_n128<0,0><<<dim3(MB,2), blk, 0, stream>>>(X, gA2_W, nullptr, H2, N_NODES, 512, 256, nullptr, nullptr);

    // 3. CSR build (also yields dinv)
    zero_kernel<<<(20000 + 255) / 256, blk, 0, stream>>>((float*)count, 20000);
    csr_count<<<1250, blk, 0, stream>>>(dst, count);
    csr_scan<<<1, 1024, 0, stream>>>(count, rowptr, cursor, dinv);
    csr_fill<<<1250, blk, 0, stream>>>(src, dst, cursor, srcs);

    // 4. gather-side aggregation, fused self-term + bias (both GCNs)
    gcn_aggregate<<<N_NODES, blk, 0, stream>>>(H1, H2, dinv, rowptr, srcs,
                                               gcn_b, gA2_b, O1, O2);

    // 5-6. projections to HIDDEN
    gemm_f32_n128<1,1><<<dim3(MB,1), blk, 0, stream>>>(O1, lin_W, lin_b, xg, N_NODES, 256, 128, nullptr, nullptr);
    gemm_f32_n128<0,1><<<dim3(MB,1), blk, 0, stream>>>(O2, tf_W, tf_b, tfe, N_NODES, 256, 128, nullptr, nullptr);
    gemm_f32_n128<0,1><<<dim3(MB,1), blk, 0, stream>>>(O2, tg_W, tg_b, tge, N_NODES, 256, 128, nullptr, nullptr);

    // 7. q / k / v
    gemm_f32_n128<2,0><<<dim3(MB,1), blk, 0, stream>>>(xg,  Wq, bq, qb, N_NODES, 128, 128, pos, pemb);
    gemm_f32_n128<2,0><<<dim3(MB,1), blk, 0, stream>>>(tfe, Wk, bk, kb, N_NODES, 128, 128, pos, pemb);
    gemm_f32_n128<0,0><<<dim3(MB,1), blk, 0, stream>>>(tge, Wv, bv, vb, N_NODES, 128, 128, nullptr, nullptr);

    // 8. kc/vc
    zero_kernel<<<256, blk, 0, stream>>>(kc, 65536);
    kcvc_kernel<<<dim3(2, KC_SPLITS, 2), blk, 0, stream>>>(Ek, Ev, kb, vb, kc, vc);

    // 9. attention
    attn_kernel<<<N_NODES, 64, 0, stream>>>(qb, kc, vc, attn);

    // 10. x_f = attn @ Wo + bo
    gemm_f32_n128<0,0><<<dim3(MB,1), blk, 0, stream>>>(attn, Wo, bo, xf, N_NODES, 128, 128, nullptr, nullptr);

    // 11. tfa / tga
    gemm_f32<0,1><<<dim3(MB,1), blk, 0, stream>>>(xf, tfaW, tfab, tfa, N_NODES, 128, 64, nullptr, nullptr);
    gemm_f32<0,1><<<dim3(MB,1), blk, 0, stream>>>(xf, tgaW, tgab, tga, N_NODES, 128, 64, nullptr, nullptr);

    // 12. cosine similarity
    cosine_kernel<<<NTRAIN / 4, blk, 0, stream>>>(tfa, tga, ts, (float*)d_out);
}

// Round 6
// 1389.842 us; speedup vs baseline: 1.6021x; 1.2387x over previous
//
#include <hip/hip_runtime.h>
#include <hip/hip_bf16.h>

#define N_NODES 20000
#define E_EDGES 320000
#define NTRAIN  200000
#define KC_SPLITS 128

// ---------------------------------------------------------------------------
// f32 LDS-tiled GEMM, BM=64 BN=64, 4x4/thread (used for N=64 outputs)
// PRE: 0 none, 1 sigmoid, 2 +pos_emb[positions[row]] ; POST: 0 none, 1 leaky
// ---------------------------------------------------------------------------
template<int PRE, int POST>
__global__ __launch_bounds__(256) void gemm_f32(
    const float* __restrict__ A, const float* __restrict__ W,
    const float* __restrict__ bias, float* __restrict__ C,
    int M, int K, int Nn,
    const int* __restrict__ positions, const float* __restrict__ pos_emb)
{
    __shared__ float As[16][68];
    __shared__ float Bs[16][64];

    const int t  = threadIdx.x;
    const int m0 = blockIdx.x * 64;
    const int n0 = blockIdx.y * 64;

    const int kl  = t & 15;
    const int ml  = t >> 4;
    const int nl  = t & 63;
    const int kl2 = t >> 6;
    const int tc  = t & 15;
    const int tr  = t >> 4;

    float acc[4][4] = {};

    for (int k0 = 0; k0 < K; k0 += 16) {
        #pragma unroll
        for (int i = 0; i < 4; i++) {
            int row = m0 + ml + i * 16;
            float v = 0.f;
            if (row < M) {
                v = A[(size_t)row * K + k0 + kl];
                if (PRE == 1) v = 1.f / (1.f + expf(-v));
                if (PRE == 2) v += pos_emb[(size_t)positions[row] * K + k0 + kl];
            }
            As[kl][ml + i * 16] = v;
        }
        #pragma unroll
        for (int i = 0; i < 4; i++) {
            int kk = kl2 * 4 + i;
            Bs[kk][nl] = W[(size_t)(k0 + kk) * Nn + n0 + nl];
        }
        __syncthreads();
        #pragma unroll
        for (int kk = 0; kk < 16; kk++) {
            float4 ra = *reinterpret_cast<const float4*>(&As[kk][tr * 4]);
            float4 rb = *reinterpret_cast<const float4*>(&Bs[kk][tc * 4]);
            float am[4] = {ra.x, ra.y, ra.z, ra.w};
            float bn[4] = {rb.x, rb.y, rb.z, rb.w};
            #pragma unroll
            for (int i = 0; i < 4; i++)
                #pragma unroll
                for (int j = 0; j < 4; j++)
                    acc[i][j] += am[i] * bn[j];
        }
        __syncthreads();
    }

    #pragma unroll
    for (int i = 0; i < 4; i++) {
        int row = m0 + tr * 4 + i;
        if (row >= M) continue;
        #pragma unroll
        for (int j = 0; j < 4; j++) {
            int col = n0 + tc * 4 + j;
            float v = acc[i][j] + (bias ? bias[col] : 0.f);
            if (POST == 1) v = (v >= 0.f) ? v : 0.01f * v;
            C[(size_t)row * Nn + col] = v;
        }
    }
}

// ---------------------------------------------------------------------------
// f32 LDS-tiled GEMM, BM=64 BN=128, 4x8/thread. Bs swizzled (+4*(col>>5)) so
// the 16-group float4 reads are 2-way on banks (free) instead of 4-way.
// ---------------------------------------------------------------------------
template<int PRE, int POST>
__global__ __launch_bounds__(256) void gemm_f32_n128(
    const float* __restrict__ A, const float* __restrict__ W,
    const float* __restrict__ bias, float* __restrict__ C,
    int M, int K, int Nn,
    const int* __restrict__ positions, const float* __restrict__ pos_emb)
{
    __shared__ float As[16][68];
    __shared__ float Bs[16][144];   // phys col = n + 4*(n>>5)

    const int t  = threadIdx.x;
    const int m0 = blockIdx.x * 64;
    const int n0 = blockIdx.y * 128;

    const int kl = t & 15;    // A-load k
    const int ml = t >> 4;    // A-load m base
    const int nl = t & 127;   // B-load n
    const int kb = t >> 7;    // B-load k base

    const int tc = t & 15;    // col group (8 cols)
    const int tr = t >> 4;    // row group (4 rows)
    const int bPhys = tc * 8 + (tc >> 2) * 4;

    float acc[4][8] = {};

    for (int k0 = 0; k0 < K; k0 += 16) {
        #pragma unroll
        for (int i = 0; i < 4; i++) {
            int row = m0 + ml + i * 16;
            float v = 0.f;
            if (row < M) {
                v = A[(size_t)row * K + k0 + kl];
                if (PRE == 1) v = 1.f / (1.f + expf(-v));
                if (PRE == 2) v += pos_emb[(size_t)positions[row] * K + k0 + kl];
            }
            As[kl][ml + i * 16] = v;
        }
        {
            int pc = nl + (nl >> 5) * 4;
            #pragma unroll
            for (int i = 0; i < 8; i++) {
                int kk = kb + i * 2;
                Bs[kk][pc] = W[(size_t)(k0 + kk) * Nn + n0 + nl];
            }
        }
        __syncthreads();
        #pragma unroll
        for (int kk = 0; kk < 16; kk++) {
            float4 ra  = *reinterpret_cast<const float4*>(&As[kk][tr * 4]);
            float4 rb0 = *reinterpret_cast<const float4*>(&Bs[kk][bPhys]);
            float4 rb1 = *reinterpret_cast<const float4*>(&Bs[kk][bPhys + 4]);
            float am[4] = {ra.x, ra.y, ra.z, ra.w};
            float bn[8] = {rb0.x, rb0.y, rb0.z, rb0.w, rb1.x, rb1.y, rb1.z, rb1.w};
            #pragma unroll
            for (int i = 0; i < 4; i++)
                #pragma unroll
                for (int j = 0; j < 8; j++)
                    acc[i][j] += am[i] * bn[j];
        }
        __syncthreads();
    }

    #pragma unroll
    for (int i = 0; i < 4; i++) {
        int row = m0 + tr * 4 + i;
        if (row >= M) continue;
        float4 o0, o1;
        float* po0 = (float*)&o0;
        float* po1 = (float*)&o1;
        #pragma unroll
        for (int j = 0; j < 4; j++) {
            float v = acc[i][j] + (bias ? bias[n0 + tc * 8 + j] : 0.f);
            if (POST == 1) v = (v >= 0.f) ? v : 0.01f * v;
            po0[j] = v;
            float w = acc[i][j + 4] + (bias ? bias[n0 + tc * 8 + 4 + j] : 0.f);
            if (POST == 1) w = (w >= 0.f) ? w : 0.01f * w;
            po1[j] = w;
        }
        *reinterpret_cast<float4*>(&C[(size_t)row * Nn + n0 + tc * 8])     = o0;
        *reinterpret_cast<float4*>(&C[(size_t)row * Nn + n0 + tc * 8 + 4]) = o1;
    }
}

__global__ void zero_kernel(float* __restrict__ p, int n)
{
    int i = blockIdx.x * 256 + threadIdx.x;
    if (i < n) p[i] = 0.f;
}

// ---------------------------------------------------------------------------
// CSR build step 1: count[n] = indegree(n)  (count pre-zeroed)
// ---------------------------------------------------------------------------
__global__ void csr_count(const int* __restrict__ dst, int* __restrict__ count)
{
    int e = blockIdx.x * 256 + threadIdx.x;
    int stride = gridDim.x * 256;
    for (; e < E_EDGES; e += stride)
        atomicAdd(&count[dst[e]], 1);
}

// ---------------------------------------------------------------------------
// CSR build step 2: single-block exclusive scan of count -> rowptr, cursor.
// Also emits dinv[n] = rsqrt(1 + indegree) (the GCN degree normalizer).
// ---------------------------------------------------------------------------
__global__ __launch_bounds__(1024) void csr_scan(
    const int* __restrict__ count, int* __restrict__ rowptr,
    int* __restrict__ cursor, float* __restrict__ dinv)
{
    __shared__ int s[1024];
    const int t = threadIdx.x;
    int carry = 0;
    for (int base = 0; base < N_NODES; base += 1024) {
        int i = base + t;
        int v = (i < N_NODES) ? count[i] : 0;
        if (i < N_NODES) dinv[i] = rsqrtf(1.f + (float)v);
        s[t] = v;
        __syncthreads();
        for (int off = 1; off < 1024; off <<= 1) {
            int add = (t >= off) ? s[t - off] : 0;
            __syncthreads();
            s[t] += add;
            __syncthreads();
        }
        int incl  = s[t];
        int total = s[1023];
        if (i < N_NODES) {
            rowptr[i] = carry + incl - v;
            cursor[i] = carry + incl - v;
        }
        carry += total;
        __syncthreads();   // s reused next iteration
    }
    if (t == 0) rowptr[N_NODES] = carry;
}

// ---------------------------------------------------------------------------
// CSR build step 3: bucket edge sources by dst
// ---------------------------------------------------------------------------
__global__ void csr_fill(const int* __restrict__ src, const int* __restrict__ dst,
                         int* __restrict__ cursor, int* __restrict__ srcs)
{
    int e = blockIdx.x * 256 + threadIdx.x;
    int stride = gridDim.x * 256;
    for (; e < E_EDGES; e += stride) {
        int slot = atomicAdd(&cursor[dst[e]], 1);
        srcs[slot] = src[e];
    }
}

// ---------------------------------------------------------------------------
// GCN aggregation, gather-side (no float atomics):
// O[n] = sum_{s in in(n)} H[s]*dinv[s]*dinv[n] + H[n]*dinv[n]^2 + b
// ---------------------------------------------------------------------------
__global__ __launch_bounds__(256) void gcn_aggregate(
    const float* __restrict__ H1, const float* __restrict__ H2,
    const float* __restrict__ dinv,
    const int* __restrict__ rowptr, const int* __restrict__ srcs,
    const float* __restrict__ b1, const float* __restrict__ b2,
    float* __restrict__ O1, float* __restrict__ O2)
{
    const int n = blockIdx.x;
    const int f = threadIdx.x;
    const float dn = dinv[n];
    const size_t nidx = (size_t)n * 256 + f;

    float a1 = H1[nidx] * dn * dn + b1[f];
    float a2 = H2[nidx] * dn * dn + b2[f];

    const int e0 = rowptr[n];
    const int e1 = rowptr[n + 1];
    for (int e = e0; e < e1; e++) {
        int s = srcs[e];
        float c = dinv[s] * dn;
        size_t si = (size_t)s * 256 + f;
        a1 += H1[si] * c;
        a2 += H2[si] * c;
    }
    O1[nidx] = a1;
    O2[nidx] = a2;
}

// ---------------------------------------------------------------------------
// kc = Ek @ k, vc = Ev @ v : (256 x 20000) @ (20000 x 128), split-K atomics.
// ---------------------------------------------------------------------------
__global__ __launch_bounds__(256) void kcvc_kernel(
    const float* __restrict__ Ek, const float* __restrict__ Ev,
    const float* __restrict__ kin, const float* __restrict__ vin,
    float* __restrict__ kc, float* __restrict__ vc)
{
    const float* E = blockIdx.z ? Ev  : Ek;
    const float* X = blockIdx.z ? vin : kin;
    float*       out = blockIdx.z ? vc : kc;

    const int c0 = blockIdx.x * 128;
    const int per = 160;                         // multiple of 32: alignment!
    const int nStart = blockIdx.y * per;
    const int nEnd   = min(nStart + per, N_NODES);

    __shared__ float Es[32][144];
    __shared__ float Xs[32][144];

    const int t  = threadIdx.x;
    const int tc = t & 15;
    const int td = t >> 4;
    const int ePhys = tc * 8 + (tc >> 2) * 4;
    const int xPhys = td * 8 + (td >> 2) * 4;

    float acc[8][8] = {};

    for (int nb = nStart; nb < nEnd; nb += 32) {
        const int nc = min(32, nEnd - nb);

        {
            int cl  = t >> 1;
            int pc  = cl + (cl >> 5) * 4;
            int nnb = (t & 1) * 16;
            const float* srcp = &E[(size_t)(c0 + cl) * N_NODES + nb + nnb];
            if (nc == 32) {
                #pragma unroll
                for (int i = 0; i < 4; i++) {
                    float4 v = *reinterpret_cast<const float4*>(&srcp[i * 4]);
                    Es[nnb + i * 4 + 0][pc] = v.x;
                    Es[nnb + i * 4 + 1][pc] = v.y;
                    Es[nnb + i * 4 + 2][pc] = v.z;
                    Es[nnb + i * 4 + 3][pc] = v.w;
                }
            } else {
                for (int i = 0; i < 16; i++) {
                    int nn = nnb + i;
                    Es[nn][pc] = (nn < nc) ? srcp[i] : 0.f;
                }
            }
        }
        {
            #pragma unroll
            for (int i = 0; i < 4; i++) {
                int g  = t + i * 256;
                int nn = g >> 5;
                int d0 = (g & 31) * 4;
                int pd = d0 + (d0 >> 5) * 4;
                if (nn < nc) {
                    float4 v = *reinterpret_cast<const float4*>(&X[(size_t)(nb + nn) * 128 + d0]);
                    Xs[nn][pd + 0] = v.x; Xs[nn][pd + 1] = v.y;
                    Xs[nn][pd + 2] = v.z; Xs[nn][pd + 3] = v.w;
                } else {
                    Xs[nn][pd + 0] = 0.f; Xs[nn][pd + 1] = 0.f;
                    Xs[nn][pd + 2] = 0.f; Xs[nn][pd + 3] = 0.f;
                }
            }
        }
        __syncthreads();

        #pragma unroll 2
        for (int nn = 0; nn < 32; nn++) {
            float4 e0 = *reinterpret_cast<const float4*>(&Es[nn][ePhys]);
            float4 e1 = *reinterpret_cast<const float4*>(&Es[nn][ePhys + 4]);
            float4 x0 = *reinterpret_cast<const float4*>(&Xs[nn][xPhys]);
            float4 x1 = *reinterpret_cast<const float4*>(&Xs[nn][xPhys + 4]);
            float ev[8] = {e0.x, e0.y, e0.z, e0.w, e1.x, e1.y, e1.z, e1.w};
            float xv[8] = {x0.x, x0.y, x0.z, x0.w, x1.x, x1.y, x1.z, x1.w};
            #pragma unroll
            for (int ci = 0; ci < 8; ci++)
                #pragma unroll
                for (int dj = 0; dj < 8; dj++)
                    acc[ci][dj] += ev[ci] * xv[dj];
        }
        __syncthreads();
    }

    #pragma unroll
    for (int ci = 0; ci < 8; ci++) {
        int c = c0 + tc * 8 + ci;
        #pragma unroll
        for (int dj = 0; dj < 8; dj++)
            atomicAdd(&out[(size_t)c * 128 + td * 8 + dj], acc[ci][dj]);
    }
}

// ---------------------------------------------------------------------------
// Fused attention v2: block = 256 threads = 16 nodes x 16 lanes, grid 1250.
// Per head: stage kc_h transposed [d][c] (lanes span c -> conflict-free),
// vc_h [c][d] pad-20 (lanes span d -> conflict-free), q [16][132].
// Score: thread (node,tn) computes 16 dots for c = tn+16j (16 indep chains).
// Softmax: shfl_xor 1/2/4/8 within the 16-lane node group.
// PV: thread (node, d=tn) sums 256 c, float4 w_s broadcast reads, 4 chains.
// ---------------------------------------------------------------------------
__global__ __launch_bounds__(256) void attn_kernel(
    const float* __restrict__ q, const float* __restrict__ kc,
    const float* __restrict__ vc, float* __restrict__ outp)
{
    __shared__ float q_s[16][132];
    __shared__ float kc_s[16][272];   // [d][c]
    __shared__ float vc_s[256][20];   // [c][d], stride 20 keeps 16B align
    __shared__ float w_s[16][264];

    const int t    = threadIdx.x;
    const int n0   = blockIdx.x * 16;
    const int node = t >> 4;
    const int tn   = t & 15;

    // stage q: 16 nodes x 128 floats, 8 per thread
    {
        const float* qp = q + (size_t)n0 * 128;
        #pragma unroll
        for (int i = 0; i < 2; i++) {
            int idx = t * 8 + i * 4;
            float4 v = *reinterpret_cast<const float4*>(&qp[idx]);
            *reinterpret_cast<float4*>(&q_s[idx >> 7][idx & 127]) = v;
        }
    }

    for (int h = 0; h < 8; h++) {
        __syncthreads();   // prev iteration's PV reads done before restage
        // stage kc_h transposed + vc_h (thread t owns row c = t)
        {
            const float* kp = &kc[(size_t)t * 128 + h * 16];
            float4 a0 = *reinterpret_cast<const float4*>(kp);
            float4 a1 = *reinterpret_cast<const float4*>(kp + 4);
            float4 a2 = *reinterpret_cast<const float4*>(kp + 8);
            float4 a3 = *reinterpret_cast<const float4*>(kp + 12);
            kc_s[ 0][t] = a0.x; kc_s[ 1][t] = a0.y; kc_s[ 2][t] = a0.z; kc_s[ 3][t] = a0.w;
            kc_s[ 4][t] = a1.x; kc_s[ 5][t] = a1.y; kc_s[ 6][t] = a1.z; kc_s[ 7][t] = a1.w;
            kc_s[ 8][t] = a2.x; kc_s[ 9][t] = a2.y; kc_s[10][t] = a2.z; kc_s[11][t] = a2.w;
            kc_s[12][t] = a3.x; kc_s[13][t] = a3.y; kc_s[14][t] = a3.z; kc_s[15][t] = a3.w;
            const float* vp = &vc[(size_t)t * 128 + h * 16];
            *reinterpret_cast<float4*>(&vc_s[t][ 0]) = *reinterpret_cast<const float4*>(vp);
            *reinterpret_cast<float4*>(&vc_s[t][ 4]) = *reinterpret_cast<const float4*>(vp + 4);
            *reinterpret_cast<float4*>(&vc_s[t][ 8]) = *reinterpret_cast<const float4*>(vp + 8);
            *reinterpret_cast<float4*>(&vc_s[t][12]) = *reinterpret_cast<const float4*>(vp + 12);
        }
        __syncthreads();

        // ---- score phase ----
        float qr[16];
        #pragma unroll
        for (int d = 0; d < 16; d++) qr[d] = q_s[node][h * 16 + d];

        float sv[16];
        #pragma unroll
        for (int j = 0; j < 16; j++) {
            int c = tn + 16 * j;
            float a = 0.f;
            #pragma unroll
            for (int d = 0; d < 16; d++)
                a += qr[d] * kc_s[d][c];
            sv[j] = a * 0.25f;
        }

        float m = sv[0];
        #pragma unroll
        for (int j = 1; j < 16; j++) m = fmaxf(m, sv[j]);
        #pragma unroll
        for (int off = 8; off > 0; off >>= 1)
            m = fmaxf(m, __shfl_xor(m, off));

        float sum = 0.f;
        #pragma unroll
        for (int j = 0; j < 16; j++) {
            sv[j] = expf(sv[j] - m);
            sum += sv[j];
        }
        #pragma unroll
        for (int off = 8; off > 0; off >>= 1)
            sum += __shfl_xor(sum, off);
        float inv = 1.0f / sum;

        #pragma unroll
        for (int j = 0; j < 16; j++)
            w_s[node][tn + 16 * j] = sv[j] * inv;
        __syncthreads();

        // ---- PV phase: out[node][h*16+tn] = sum_c w[c] * vc[c][tn] ----
        float acc0 = 0.f, acc1 = 0.f, acc2 = 0.f, acc3 = 0.f;
        #pragma unroll 4
        for (int cb = 0; cb < 64; cb++) {
            int c = cb * 4;
            float4 w4 = *reinterpret_cast<const float4*>(&w_s[node][c]);
            acc0 += w4.x * vc_s[c + 0][tn];
            acc1 += w4.y * vc_s[c + 1][tn];
            acc2 += w4.z * vc_s[c + 2][tn];
            acc3 += w4.w * vc_s[c + 3][tn];
        }
        outp[(size_t)(n0 + node) * 128 + h * 16 + tn] = (acc0 + acc1) + (acc2 + acc3);
    }
}

// ---------------------------------------------------------------------------
// Cosine similarity: one wave per pair, 64 lanes = 64 features
// ---------------------------------------------------------------------------
__global__ __launch_bounds__(256) void cosine_kernel(
    const float* __restrict__ tfa, const float* __restrict__ tga,
    const int* __restrict__ ts, float* __restrict__ out)
{
    const int w    = threadIdx.x >> 6;
    const int lane = threadIdx.x & 63;
    const int t    = blockIdx.x * 4 + w;
    if (t >= NTRAIN) return;

    int i = ts[2 * t];
    int j = ts[2 * t + 1];
    float a = tfa[(size_t)i * 64 + lane];
    float b = tga[(size_t)j * 64 + lane];
    float da = a * b, na = a * a, nb = b * b;
    #pragma unroll
    for (int off = 32; off > 0; off >>= 1) {
        da += __shfl_xor(da, off);
        na += __shfl_xor(na, off);
        nb += __shfl_xor(nb, off);
    }
    if (lane == 0)
        out[t] = da / fmaxf(sqrtf(na) * sqrtf(nb), 1e-8f);
}

// ---------------------------------------------------------------------------
extern "C" void kernel_launch(void* const* d_in, const int* in_sizes, int n_in,
                              void* d_out, int out_size, void* d_ws, size_t ws_size,
                              hipStream_t stream)
{
    const int*   ts    = (const int*)  d_in[1];
    const float* X     = (const float*)d_in[2];
    const int*   adj   = (const int*)  d_in[3];
    const int*   pos   = (const int*)  d_in[4];
    const float* gcn_W = (const float*)d_in[5];
    const float* gcn_b = (const float*)d_in[6];
    const float* gA2_W = (const float*)d_in[7];
    const float* gA2_b = (const float*)d_in[8];
    const float* lin_W = (const float*)d_in[9];
    const float* lin_b = (const float*)d_in[10];
    const float* tf_W  = (const float*)d_in[11];
    const float* tf_b  = (const float*)d_in[12];
    const float* tg_W  = (const float*)d_in[13];
    const float* tg_b  = (const float*)d_in[14];
    const float* Wq    = (const float*)d_in[15];
    const float* bq    = (const float*)d_in[16];
    const float* Wk    = (const float*)d_in[17];
    const float* bk    = (const float*)d_in[18];
    const float* Wv    = (const float*)d_in[19];
    const float* bv    = (const float*)d_in[20];
    const float* Wo    = (const float*)d_in[21];
    const float* bo    = (const float*)d_in[22];
    const float* Ek    = (const float*)d_in[23];
    const float* Ev    = (const float*)d_in[24];
    const float* pemb  = (const float*)d_in[25];
    const float* tfaW  = (const float*)d_in[26];
    const float* tfab  = (const float*)d_in[27];
    const float* tgaW  = (const float*)d_in[28];
    const float* tgab  = (const float*)d_in[29];

    const int* src = adj;
    const int* dst = adj + E_EDGES;

    float* ws  = (float*)d_ws;
    float* H1  = ws;                 // 20000*256
    float* H2  = H1 + 5120000;
    float* O1  = H2 + 5120000;
    float* O2  = O1 + 5120000;
    float* dinv = O2 + 5120000;      // 20000
    float* kc  = dinv + 20000;       // 256*128
    float* vc  = kc + 32768;         // 256*128
    int*   count  = (int*)(vc + 32768);     // 20000
    int*   rowptr = count + 20000;          // 20001
    int*   cursor = rowptr + 20001;         // 20000
    int*   srcs   = cursor + 20000;         // 320000
    // aliases over dead buffers:
    float* xg   = H1;
    float* tfe  = H1 + 2560000;
    float* tge  = H2;
    float* qb   = H2 + 2560000;
    float* kb   = O1;
    float* vb   = O1 + 2560000;
    float* attn = O2;
    float* xf   = O2 + 2560000;
    float* tfa  = H1;
    float* tga  = H1 + 1280000;

    dim3 blk(256);
    const int MB = (N_NODES + 63) / 64;   // 313

    // 1-2. H1 = X @ gcn_W ; H2 = X @ gcnA2_W
    gemm_f32_n128<0,0><<<dim3(MB,2), blk, 0, stream>>>(X, gcn_W, nullptr, H1, N_NODES, 512, 256, nullptr, nullptr);
    gemm_f32_n128<0,0><<<dim3(MB,2), blk, 0, stream>>>(X, gA2_W, nullptr, H2, N_NODES, 512, 256, nullptr, nullptr);

    // 3. CSR build (also yields dinv)
    zero_kernel<<<(20000 + 255) / 256, blk, 0, stream>>>((float*)count, 20000);
    csr_count<<<1250, blk, 0, stream>>>(dst, count);
    csr_scan<<<1, 1024, 0, stream>>>(count, rowptr, cursor, dinv);
    csr_fill<<<1250, blk, 0, stream>>>(src, dst, cursor, srcs);

    // 4. gather-side aggregation, fused self-term + bias (both GCNs)
    gcn_aggregate<<<N_NODES, blk, 0, stream>>>(H1, H2, dinv, rowptr, srcs,
                                               gcn_b, gA2_b, O1, O2);

    // 5-6. projections to HIDDEN
    gemm_f32_n128<1,1><<<dim3(MB,1), blk, 0, stream>>>(O1, lin_W, lin_b, xg, N_NODES, 256, 128, nullptr, nullptr);
    gemm_f32_n128<0,1><<<dim3(MB,1), blk, 0, stream>>>(O2, tf_W, tf_b, tfe, N_NODES, 256, 128, nullptr, nullptr);
    gemm_f32_n128<0,1><<<dim3(MB,1), blk, 0, stream>>>(O2, tg_W, tg_b, tge, N_NODES, 256, 128, nullptr, nullptr);

    // 7. q / k / v
    gemm_f32_n128<2,0><<<dim3(MB,1), blk, 0, stream>>>(xg,  Wq, bq, qb, N_NODES, 128, 128, pos, pemb);
    gemm_f32_n128<2,0><<<dim3(MB,1), blk, 0, stream>>>(tfe, Wk, bk, kb, N_NODES, 128, 128, pos, pemb);
    gemm_f32_n128<0,0><<<dim3(MB,1), blk, 0, stream>>>(tge, Wv, bv, vb, N_NODES, 128, 128, nullptr, nullptr);

    // 8. kc/vc
    zero_kernel<<<256, blk, 0, stream>>>(kc, 65536);
    kcvc_kernel<<<dim3(2, KC_SPLITS, 2), blk, 0, stream>>>(Ek, Ev, kb, vb, kc, vc);

    // 9. attention (16 nodes/block, 1250 blocks)
    attn_kernel<<<1250, blk, 0, stream>>>(qb, kc, vc, attn);

    // 10. x_f = attn @ Wo + bo
    gemm_f32_n128<0,0><<<dim3(MB,1), blk, 0, stream>>>(attn, Wo, bo, xf, N_NODES, 128, 128, nullptr, nullptr);

    // 11. tfa / tga
    gemm_f32<0,1><<<dim3(MB,1), blk, 0, stream>>>(xf, tfaW, tfab, tfa, N_NODES, 128, 64, nullptr, nullptr);
    gemm_f32<0,1><<<dim3(MB,1), blk, 0, stream>>>(xf, tgaW, tgab, tga, N_NODES, 128, 64, nullptr, nullptr);

    // 12. cosine similarity
    cosine_kernel<<<NTRAIN / 4, blk, 0, stream>>>(tfa, tga, ts, (float*)d_out);
}

// Round 7
// 1075.604 us; speedup vs baseline: 2.0702x; 1.2922x over previous
//
#include <hip/hip_runtime.h>
#include <hip/hip_bf16.h>

#define N_NODES 20000
#define E_EDGES 320000
#define NTRAIN  200000
#define KC_SPLITS 64

// ---------------------------------------------------------------------------
// f32 LDS-tiled GEMM, BM=64 BN=64, 4x4/thread (used for N=64 outputs)
// PRE: 0 none, 1 sigmoid, 2 +pos_emb[positions[row]] ; POST: 0 none, 1 leaky
// ---------------------------------------------------------------------------
template<int PRE, int POST>
__global__ __launch_bounds__(256) void gemm_f32(
    const float* __restrict__ A, const float* __restrict__ W,
    const float* __restrict__ bias, float* __restrict__ C,
    int M, int K, int Nn,
    const int* __restrict__ positions, const float* __restrict__ pos_emb)
{
    __shared__ float As[16][68];
    __shared__ float Bs[16][64];

    const int t  = threadIdx.x;
    const int m0 = blockIdx.x * 64;
    const int n0 = blockIdx.y * 64;

    const int kl  = t & 15;
    const int ml  = t >> 4;
    const int nl  = t & 63;
    const int kl2 = t >> 6;
    const int tc  = t & 15;
    const int tr  = t >> 4;

    float acc[4][4] = {};

    for (int k0 = 0; k0 < K; k0 += 16) {
        #pragma unroll
        for (int i = 0; i < 4; i++) {
            int row = m0 + ml + i * 16;
            float v = 0.f;
            if (row < M) {
                v = A[(size_t)row * K + k0 + kl];
                if (PRE == 1) v = 1.f / (1.f + expf(-v));
                if (PRE == 2) v += pos_emb[(size_t)positions[row] * K + k0 + kl];
            }
            As[kl][ml + i * 16] = v;
        }
        #pragma unroll
        for (int i = 0; i < 4; i++) {
            int kk = kl2 * 4 + i;
            Bs[kk][nl] = W[(size_t)(k0 + kk) * Nn + n0 + nl];
        }
        __syncthreads();
        #pragma unroll
        for (int kk = 0; kk < 16; kk++) {
            float4 ra = *reinterpret_cast<const float4*>(&As[kk][tr * 4]);
            float4 rb = *reinterpret_cast<const float4*>(&Bs[kk][tc * 4]);
            float am[4] = {ra.x, ra.y, ra.z, ra.w};
            float bn[4] = {rb.x, rb.y, rb.z, rb.w};
            #pragma unroll
            for (int i = 0; i < 4; i++)
                #pragma unroll
                for (int j = 0; j < 4; j++)
                    acc[i][j] += am[i] * bn[j];
        }
        __syncthreads();
    }

    #pragma unroll
    for (int i = 0; i < 4; i++) {
        int row = m0 + tr * 4 + i;
        if (row >= M) continue;
        #pragma unroll
        for (int j = 0; j < 4; j++) {
            int col = n0 + tc * 4 + j;
            float v = acc[i][j] + (bias ? bias[col] : 0.f);
            if (POST == 1) v = (v >= 0.f) ? v : 0.01f * v;
            C[(size_t)row * Nn + col] = v;
        }
    }
}

// ---------------------------------------------------------------------------
// f32 LDS-tiled GEMM, BM=64 BN=128, 4x8/thread. Bs swizzled (+4*(col>>5)) so
// the 16-group float4 reads are 2-way on banks (free) instead of 4-way.
// ---------------------------------------------------------------------------
template<int PRE, int POST>
__global__ __launch_bounds__(256) void gemm_f32_n128(
    const float* __restrict__ A, const float* __restrict__ W,
    const float* __restrict__ bias, float* __restrict__ C,
    int M, int K, int Nn,
    const int* __restrict__ positions, const float* __restrict__ pos_emb)
{
    __shared__ float As[16][68];
    __shared__ float Bs[16][144];   // phys col = n + 4*(n>>5)

    const int t  = threadIdx.x;
    const int m0 = blockIdx.x * 64;
    const int n0 = blockIdx.y * 128;

    const int kl = t & 15;    // A-load k
    const int ml = t >> 4;    // A-load m base
    const int nl = t & 127;   // B-load n
    const int kb = t >> 7;    // B-load k base

    const int tc = t & 15;    // col group (8 cols)
    const int tr = t >> 4;    // row group (4 rows)
    const int bPhys = tc * 8 + (tc >> 2) * 4;

    float acc[4][8] = {};

    for (int k0 = 0; k0 < K; k0 += 16) {
        #pragma unroll
        for (int i = 0; i < 4; i++) {
            int row = m0 + ml + i * 16;
            float v = 0.f;
            if (row < M) {
                v = A[(size_t)row * K + k0 + kl];
                if (PRE == 1) v = 1.f / (1.f + expf(-v));
                if (PRE == 2) v += pos_emb[(size_t)positions[row] * K + k0 + kl];
            }
            As[kl][ml + i * 16] = v;
        }
        {
            int pc = nl + (nl >> 5) * 4;
            #pragma unroll
            for (int i = 0; i < 8; i++) {
                int kk = kb + i * 2;
                Bs[kk][pc] = W[(size_t)(k0 + kk) * Nn + n0 + nl];
            }
        }
        __syncthreads();
        #pragma unroll
        for (int kk = 0; kk < 16; kk++) {
            float4 ra  = *reinterpret_cast<const float4*>(&As[kk][tr * 4]);
            float4 rb0 = *reinterpret_cast<const float4*>(&Bs[kk][bPhys]);
            float4 rb1 = *reinterpret_cast<const float4*>(&Bs[kk][bPhys + 4]);
            float am[4] = {ra.x, ra.y, ra.z, ra.w};
            float bn[8] = {rb0.x, rb0.y, rb0.z, rb0.w, rb1.x, rb1.y, rb1.z, rb1.w};
            #pragma unroll
            for (int i = 0; i < 4; i++)
                #pragma unroll
                for (int j = 0; j < 8; j++)
                    acc[i][j] += am[i] * bn[j];
        }
        __syncthreads();
    }

    #pragma unroll
    for (int i = 0; i < 4; i++) {
        int row = m0 + tr * 4 + i;
        if (row >= M) continue;
        float4 o0, o1;
        float* po0 = (float*)&o0;
        float* po1 = (float*)&o1;
        #pragma unroll
        for (int j = 0; j < 4; j++) {
            float v = acc[i][j] + (bias ? bias[n0 + tc * 8 + j] : 0.f);
            if (POST == 1) v = (v >= 0.f) ? v : 0.01f * v;
            po0[j] = v;
            float w = acc[i][j + 4] + (bias ? bias[n0 + tc * 8 + 4 + j] : 0.f);
            if (POST == 1) w = (w >= 0.f) ? w : 0.01f * w;
            po1[j] = w;
        }
        *reinterpret_cast<float4*>(&C[(size_t)row * Nn + n0 + tc * 8])     = o0;
        *reinterpret_cast<float4*>(&C[(size_t)row * Nn + n0 + tc * 8 + 4]) = o1;
    }
}

__global__ void zero_kernel(float* __restrict__ p, int n)
{
    int i = blockIdx.x * 256 + threadIdx.x;
    if (i < n) p[i] = 0.f;
}

// ---------------------------------------------------------------------------
// CSR build step 1: count[n] = indegree(n)  (count pre-zeroed)
// ---------------------------------------------------------------------------
__global__ void csr_count(const int* __restrict__ dst, int* __restrict__ count)
{
    int e = blockIdx.x * 256 + threadIdx.x;
    int stride = gridDim.x * 256;
    for (; e < E_EDGES; e += stride)
        atomicAdd(&count[dst[e]], 1);
}

// ---------------------------------------------------------------------------
// CSR build step 2: single-block exclusive scan of count -> rowptr, cursor.
// Also emits dinv[n] = rsqrt(1 + indegree) (the GCN degree normalizer).
// ---------------------------------------------------------------------------
__global__ __launch_bounds__(1024) void csr_scan(
    const int* __restrict__ count, int* __restrict__ rowptr,
    int* __restrict__ cursor, float* __restrict__ dinv)
{
    __shared__ int s[1024];
    const int t = threadIdx.x;
    int carry = 0;
    for (int base = 0; base < N_NODES; base += 1024) {
        int i = base + t;
        int v = (i < N_NODES) ? count[i] : 0;
        if (i < N_NODES) dinv[i] = rsqrtf(1.f + (float)v);
        s[t] = v;
        __syncthreads();
        for (int off = 1; off < 1024; off <<= 1) {
            int add = (t >= off) ? s[t - off] : 0;
            __syncthreads();
            s[t] += add;
            __syncthreads();
        }
        int incl  = s[t];
        int total = s[1023];
        if (i < N_NODES) {
            rowptr[i] = carry + incl - v;
            cursor[i] = carry + incl - v;
        }
        carry += total;
        __syncthreads();   // s reused next iteration
    }
    if (t == 0) rowptr[N_NODES] = carry;
}

// ---------------------------------------------------------------------------
// CSR build step 3: bucket edge sources by dst
// ---------------------------------------------------------------------------
__global__ void csr_fill(const int* __restrict__ src, const int* __restrict__ dst,
                         int* __restrict__ cursor, int* __restrict__ srcs)
{
    int e = blockIdx.x * 256 + threadIdx.x;
    int stride = gridDim.x * 256;
    for (; e < E_EDGES; e += stride) {
        int slot = atomicAdd(&cursor[dst[e]], 1);
        srcs[slot] = src[e];
    }
}

// ---------------------------------------------------------------------------
// GCN aggregation, gather-side (no float atomics):
// O[n] = sum_{s in in(n)} H[s]*dinv[s]*dinv[n] + H[n]*dinv[n]^2 + b
// ---------------------------------------------------------------------------
__global__ __launch_bounds__(256) void gcn_aggregate(
    const float* __restrict__ H1, const float* __restrict__ H2,
    const float* __restrict__ dinv,
    const int* __restrict__ rowptr, const int* __restrict__ srcs,
    const float* __restrict__ b1, const float* __restrict__ b2,
    float* __restrict__ O1, float* __restrict__ O2)
{
    const int n = blockIdx.x;
    const int f = threadIdx.x;
    const float dn = dinv[n];
    const size_t nidx = (size_t)n * 256 + f;

    float a1 = H1[nidx] * dn * dn + b1[f];
    float a2 = H2[nidx] * dn * dn + b2[f];

    const int e0 = rowptr[n];
    const int e1 = rowptr[n + 1];
    for (int e = e0; e < e1; e++) {
        int s = srcs[e];
        float c = dinv[s] * dn;
        size_t si = (size_t)s * 256 + f;
        a1 += H1[si] * c;
        a2 += H2[si] * c;
    }
    O1[nidx] = a1;
    O2[nidx] = a2;
}

// ---------------------------------------------------------------------------
// kc/vc stage 1: (256 x 20000) @ (20000 x 128), split-K WITHOUT atomics.
// grid = (2 c-tiles, KC_SPLITS, 2 matrices). Each block writes its 128x128
// partial tile to partial[mat][split][c][d] with plain cached float4 stores
// (L2 write-combines; no device-atomic write-through storm).
// per-split chunk = 320 (multiple of 32 -> all float4 loads stay 16B-aligned).
// ---------------------------------------------------------------------------
__global__ __launch_bounds__(256) void kcvc_kernel(
    const float* __restrict__ Ek, const float* __restrict__ Ev,
    const float* __restrict__ kin, const float* __restrict__ vin,
    float* __restrict__ partial)
{
    const float* E = blockIdx.z ? Ev  : Ek;
    const float* X = blockIdx.z ? vin : kin;

    const int c0 = blockIdx.x * 128;
    const int per = 320;                         // multiple of 32: alignment!
    const int nStart = blockIdx.y * per;
    const int nEnd   = min(nStart + per, N_NODES);

    __shared__ float Es[32][144];
    __shared__ float Xs[32][144];

    const int t  = threadIdx.x;
    const int tc = t & 15;
    const int td = t >> 4;
    const int ePhys = tc * 8 + (tc >> 2) * 4;
    const int xPhys = td * 8 + (td >> 2) * 4;

    float acc[8][8] = {};

    for (int nb = nStart; nb < nEnd; nb += 32) {
        const int nc = min(32, nEnd - nb);

        {
            int cl  = t >> 1;
            int pc  = cl + (cl >> 5) * 4;
            int nnb = (t & 1) * 16;
            const float* srcp = &E[(size_t)(c0 + cl) * N_NODES + nb + nnb];
            if (nc == 32) {
                #pragma unroll
                for (int i = 0; i < 4; i++) {
                    float4 v = *reinterpret_cast<const float4*>(&srcp[i * 4]);
                    Es[nnb + i * 4 + 0][pc] = v.x;
                    Es[nnb + i * 4 + 1][pc] = v.y;
                    Es[nnb + i * 4 + 2][pc] = v.z;
                    Es[nnb + i * 4 + 3][pc] = v.w;
                }
            } else {
                for (int i = 0; i < 16; i++) {
                    int nn = nnb + i;
                    Es[nn][pc] = (nn < nc) ? srcp[i] : 0.f;
                }
            }
        }
        {
            #pragma unroll
            for (int i = 0; i < 4; i++) {
                int g  = t + i * 256;
                int nn = g >> 5;
                int d0 = (g & 31) * 4;
                int pd = d0 + (d0 >> 5) * 4;
                if (nn < nc) {
                    float4 v = *reinterpret_cast<const float4*>(&X[(size_t)(nb + nn) * 128 + d0]);
                    Xs[nn][pd + 0] = v.x; Xs[nn][pd + 1] = v.y;
                    Xs[nn][pd + 2] = v.z; Xs[nn][pd + 3] = v.w;
                } else {
                    Xs[nn][pd + 0] = 0.f; Xs[nn][pd + 1] = 0.f;
                    Xs[nn][pd + 2] = 0.f; Xs[nn][pd + 3] = 0.f;
                }
            }
        }
        __syncthreads();

        #pragma unroll 2
        for (int nn = 0; nn < 32; nn++) {
            float4 e0 = *reinterpret_cast<const float4*>(&Es[nn][ePhys]);
            float4 e1 = *reinterpret_cast<const float4*>(&Es[nn][ePhys + 4]);
            float4 x0 = *reinterpret_cast<const float4*>(&Xs[nn][xPhys]);
            float4 x1 = *reinterpret_cast<const float4*>(&Xs[nn][xPhys + 4]);
            float ev[8] = {e0.x, e0.y, e0.z, e0.w, e1.x, e1.y, e1.z, e1.w};
            float xv[8] = {x0.x, x0.y, x0.z, x0.w, x1.x, x1.y, x1.z, x1.w};
            #pragma unroll
            for (int ci = 0; ci < 8; ci++)
                #pragma unroll
                for (int dj = 0; dj < 8; dj++)
                    acc[ci][dj] += ev[ci] * xv[dj];
        }
        __syncthreads();
    }

    // plain cached stores of this block's 128x128 tile into its split slice
    float* pb = partial + ((size_t)(blockIdx.z * KC_SPLITS + blockIdx.y)) * 32768;
    #pragma unroll
    for (int ci = 0; ci < 8; ci++) {
        int c = c0 + tc * 8 + ci;
        float4 v0 = {acc[ci][0], acc[ci][1], acc[ci][2], acc[ci][3]};
        float4 v1 = {acc[ci][4], acc[ci][5], acc[ci][6], acc[ci][7]};
        *reinterpret_cast<float4*>(&pb[(size_t)c * 128 + td * 8])     = v0;
        *reinterpret_cast<float4*>(&pb[(size_t)c * 128 + td * 8 + 4]) = v1;
    }
}

// ---------------------------------------------------------------------------
// kc/vc stage 2: out[mat][c][d] = sum_s partial[mat][s][c][d]
// 16384 threads, one float4 output each; kc/vc contiguous in out.
// ---------------------------------------------------------------------------
__global__ __launch_bounds__(256) void kcvc_reduce(
    const float* __restrict__ partial, float* __restrict__ out)
{
    int i4  = blockIdx.x * 256 + threadIdx.x;    // [0, 16384)
    int mat = i4 >> 13;                          // 8192 float4 per matrix
    int off = (i4 & 8191) * 4;
    const float* p = partial + (size_t)mat * KC_SPLITS * 32768 + off;
    float4 acc = {0.f, 0.f, 0.f, 0.f};
    #pragma unroll 8
    for (int s = 0; s < KC_SPLITS; s++) {
        float4 v = *reinterpret_cast<const float4*>(p + (size_t)s * 32768);
        acc.x += v.x; acc.y += v.y; acc.z += v.z; acc.w += v.w;
    }
    *reinterpret_cast<float4*>(out + (size_t)mat * 32768 + off) = acc;
}

// ---------------------------------------------------------------------------
// Fused attention v2: block = 256 threads = 16 nodes x 16 lanes, grid 1250.
// ---------------------------------------------------------------------------
__global__ __launch_bounds__(256) void attn_kernel(
    const float* __restrict__ q, const float* __restrict__ kc,
    const float* __restrict__ vc, float* __restrict__ outp)
{
    __shared__ float q_s[16][132];
    __shared__ float kc_s[16][272];   // [d][c]
    __shared__ float vc_s[256][20];   // [c][d], stride 20 keeps 16B align
    __shared__ float w_s[16][264];

    const int t    = threadIdx.x;
    const int n0   = blockIdx.x * 16;
    const int node = t >> 4;
    const int tn   = t & 15;

    {
        const float* qp = q + (size_t)n0 * 128;
        #pragma unroll
        for (int i = 0; i < 2; i++) {
            int idx = t * 8 + i * 4;
            float4 v = *reinterpret_cast<const float4*>(&qp[idx]);
            *reinterpret_cast<float4*>(&q_s[idx >> 7][idx & 127]) = v;
        }
    }

    for (int h = 0; h < 8; h++) {
        __syncthreads();
        {
            const float* kp = &kc[(size_t)t * 128 + h * 16];
            float4 a0 = *reinterpret_cast<const float4*>(kp);
            float4 a1 = *reinterpret_cast<const float4*>(kp + 4);
            float4 a2 = *reinterpret_cast<const float4*>(kp + 8);
            float4 a3 = *reinterpret_cast<const float4*>(kp + 12);
            kc_s[ 0][t] = a0.x; kc_s[ 1][t] = a0.y; kc_s[ 2][t] = a0.z; kc_s[ 3][t] = a0.w;
            kc_s[ 4][t] = a1.x; kc_s[ 5][t] = a1.y; kc_s[ 6][t] = a1.z; kc_s[ 7][t] = a1.w;
            kc_s[ 8][t] = a2.x; kc_s[ 9][t] = a2.y; kc_s[10][t] = a2.z; kc_s[11][t] = a2.w;
            kc_s[12][t] = a3.x; kc_s[13][t] = a3.y; kc_s[14][t] = a3.z; kc_s[15][t] = a3.w;
            const float* vp = &vc[(size_t)t * 128 + h * 16];
            *reinterpret_cast<float4*>(&vc_s[t][ 0]) = *reinterpret_cast<const float4*>(vp);
            *reinterpret_cast<float4*>(&vc_s[t][ 4]) = *reinterpret_cast<const float4*>(vp + 4);
            *reinterpret_cast<float4*>(&vc_s[t][ 8]) = *reinterpret_cast<const float4*>(vp + 8);
            *reinterpret_cast<float4*>(&vc_s[t][12]) = *reinterpret_cast<const float4*>(vp + 12);
        }
        __syncthreads();

        float qr[16];
        #pragma unroll
        for (int d = 0; d < 16; d++) qr[d] = q_s[node][h * 16 + d];

        float sv[16];
        #pragma unroll
        for (int j = 0; j < 16; j++) {
            int c = tn + 16 * j;
            float a = 0.f;
            #pragma unroll
            for (int d = 0; d < 16; d++)
                a += qr[d] * kc_s[d][c];
            sv[j] = a * 0.25f;
        }

        float m = sv[0];
        #pragma unroll
        for (int j = 1; j < 16; j++) m = fmaxf(m, sv[j]);
        #pragma unroll
        for (int off = 8; off > 0; off >>= 1)
            m = fmaxf(m, __shfl_xor(m, off));

        float sum = 0.f;
        #pragma unroll
        for (int j = 0; j < 16; j++) {
            sv[j] = expf(sv[j] - m);
            sum += sv[j];
        }
        #pragma unroll
        for (int off = 8; off > 0; off >>= 1)
            sum += __shfl_xor(sum, off);
        float inv = 1.0f / sum;

        #pragma unroll
        for (int j = 0; j < 16; j++)
            w_s[node][tn + 16 * j] = sv[j] * inv;
        __syncthreads();

        float acc0 = 0.f, acc1 = 0.f, acc2 = 0.f, acc3 = 0.f;
        #pragma unroll 4
        for (int cb = 0; cb < 64; cb++) {
            int c = cb * 4;
            float4 w4 = *reinterpret_cast<const float4*>(&w_s[node][c]);
            acc0 += w4.x * vc_s[c + 0][tn];
            acc1 += w4.y * vc_s[c + 1][tn];
            acc2 += w4.z * vc_s[c + 2][tn];
            acc3 += w4.w * vc_s[c + 3][tn];
        }
        outp[(size_t)(n0 + node) * 128 + h * 16 + tn] = (acc0 + acc1) + (acc2 + acc3);
    }
}

// ---------------------------------------------------------------------------
// Cosine similarity: one wave per pair, 64 lanes = 64 features
// ---------------------------------------------------------------------------
__global__ __launch_bounds__(256) void cosine_kernel(
    const float* __restrict__ tfa, const float* __restrict__ tga,
    const int* __restrict__ ts, float* __restrict__ out)
{
    const int w    = threadIdx.x >> 6;
    const int lane = threadIdx.x & 63;
    const int t    = blockIdx.x * 4 + w;
    if (t >= NTRAIN) return;

    int i = ts[2 * t];
    int j = ts[2 * t + 1];
    float a = tfa[(size_t)i * 64 + lane];
    float b = tga[(size_t)j * 64 + lane];
    float da = a * b, na = a * a, nb = b * b;
    #pragma unroll
    for (int off = 32; off > 0; off >>= 1) {
        da += __shfl_xor(da, off);
        na += __shfl_xor(na, off);
        nb += __shfl_xor(nb, off);
    }
    if (lane == 0)
        out[t] = da / fmaxf(sqrtf(na) * sqrtf(nb), 1e-8f);
}

// ---------------------------------------------------------------------------
extern "C" void kernel_launch(void* const* d_in, const int* in_sizes, int n_in,
                              void* d_out, int out_size, void* d_ws, size_t ws_size,
                              hipStream_t stream)
{
    const int*   ts    = (const int*)  d_in[1];
    const float* X     = (const float*)d_in[2];
    const int*   adj   = (const int*)  d_in[3];
    const int*   pos   = (const int*)  d_in[4];
    const float* gcn_W = (const float*)d_in[5];
    const float* gcn_b = (const float*)d_in[6];
    const float* gA2_W = (const float*)d_in[7];
    const float* gA2_b = (const float*)d_in[8];
    const float* lin_W = (const float*)d_in[9];
    const float* lin_b = (const float*)d_in[10];
    const float* tf_W  = (const float*)d_in[11];
    const float* tf_b  = (const float*)d_in[12];
    const float* tg_W  = (const float*)d_in[13];
    const float* tg_b  = (const float*)d_in[14];
    const float* Wq    = (const float*)d_in[15];
    const float* bq    = (const float*)d_in[16];
    const float* Wk    = (const float*)d_in[17];
    const float* bk    = (const float*)d_in[18];
    const float* Wv    = (const float*)d_in[19];
    const float* bv    = (const float*)d_in[20];
    const float* Wo    = (const float*)d_in[21];
    const float* bo    = (const float*)d_in[22];
    const float* Ek    = (const float*)d_in[23];
    const float* Ev    = (const float*)d_in[24];
    const float* pemb  = (const float*)d_in[25];
    const float* tfaW  = (const float*)d_in[26];
    const float* tfab  = (const float*)d_in[27];
    const float* tgaW  = (const float*)d_in[28];
    const float* tgab  = (const float*)d_in[29];

    const int* src = adj;
    const int* dst = adj + E_EDGES;

    float* ws  = (float*)d_ws;
    float* H1  = ws;                 // 20000*256
    float* H2  = H1 + 5120000;
    float* O1  = H2 + 5120000;
    float* O2  = O1 + 5120000;
    float* dinv = O2 + 5120000;      // 20000
    float* kc  = dinv + 20000;       // 256*128
    float* vc  = kc + 32768;         // 256*128
    int*   count  = (int*)(vc + 32768);     // 20000
    int*   rowptr = count + 20000;          // 20001
    int*   cursor = rowptr + 20001;         // 20000
    int*   srcs   = cursor + 20000;         // 320000
    // aliases over dead buffers:
    float* xg   = H1;
    float* tfe  = H1 + 2560000;
    float* tge  = H2;
    float* qb   = H2 + 2560000;
    float* kb   = O1;
    float* vb   = O1 + 2560000;
    float* attn = O2;
    float* xf   = O2 + 2560000;
    float* tfa  = H1;
    float* tga  = H1 + 1280000;
    // kcvc split-K partials: 2*KC_SPLITS*32768 = 4.19M floats, overlays H1
    // (xg/tfe are consumed by the q/k GEMMs which run before kcvc stage 1;
    //  tfa/tga re-alias H1 only after kcvc_reduce is done)
    float* partial = H1;

    dim3 blk(256);
    const int MB = (N_NODES + 63) / 64;   // 313

    // 1-2. H1 = X @ gcn_W ; H2 = X @ gcnA2_W
    gemm_f32_n128<0,0><<<dim3(MB,2), blk, 0, stream>>>(X, gcn_W, nullptr, H1, N_NODES, 512, 256, nullptr, nullptr);
    gemm_f32_n128<0,0><<<dim3(MB,2), blk, 0, stream>>>(X, gA2_W, nullptr, H2, N_NODES, 512, 256, nullptr, nullptr);

    // 3. CSR build (also yields dinv)
    zero_kernel<<<(20000 + 255) / 256, blk, 0, stream>>>((float*)count, 20000);
    csr_count<<<1250, blk, 0, stream>>>(dst, count);
    csr_scan<<<1, 1024, 0, stream>>>(count, rowptr, cursor, dinv);
    csr_fill<<<1250, blk, 0, stream>>>(src, dst, cursor, srcs);

    // 4. gather-side aggregation, fused self-term + bias (both GCNs)
    gcn_aggregate<<<N_NODES, blk, 0, stream>>>(H1, H2, dinv, rowptr, srcs,
                                               gcn_b, gA2_b, O1, O2);

    // 5-6. projections to HIDDEN
    gemm_f32_n128<1,1><<<dim3(MB,1), blk, 0, stream>>>(O1, lin_W, lin_b, xg, N_NODES, 256, 128, nullptr, nullptr);
    gemm_f32_n128<0,1><<<dim3(MB,1), blk, 0, stream>>>(O2, tf_W, tf_b, tfe, N_NODES, 256, 128, nullptr, nullptr);
    gemm_f32_n128<0,1><<<dim3(MB,1), blk, 0, stream>>>(O2, tg_W, tg_b, tge, N_NODES, 256, 128, nullptr, nullptr);

    // 7. q / k / v
    gemm_f32_n128<2,0><<<dim3(MB,1), blk, 0, stream>>>(xg,  Wq, bq, qb, N_NODES, 128, 128, pos, pemb);
    gemm_f32_n128<2,0><<<dim3(MB,1), blk, 0, stream>>>(tfe, Wk, bk, kb, N_NODES, 128, 128, pos, pemb);
    gemm_f32_n128<0,0><<<dim3(MB,1), blk, 0, stream>>>(tge, Wv, bv, vb, N_NODES, 128, 128, nullptr, nullptr);

    // 8. kc/vc: split-K partials (no atomics) + reduce
    kcvc_kernel<<<dim3(2, KC_SPLITS, 2), blk, 0, stream>>>(Ek, Ev, kb, vb, partial);
    kcvc_reduce<<<64, blk, 0, stream>>>(partial, kc);

    // 9. attention (16 nodes/block, 1250 blocks)
    attn_kernel<<<1250, blk, 0, stream>>>(qb, kc, vc, attn);

    // 10. x_f = attn @ Wo + bo
    gemm_f32_n128<0,0><<<dim3(MB,1), blk, 0, stream>>>(attn, Wo, bo, xf, N_NODES, 128, 128, nullptr, nullptr);

    // 11. tfa / tga
    gemm_f32<0,1><<<dim3(MB,1), blk, 0, stream>>>(xf, tfaW, tfab, tfa, N_NODES, 128, 64, nullptr, nullptr);
    gemm_f32<0,1><<<dim3(MB,1), blk, 0, stream>>>(xf, tgaW, tgab, tga, N_NODES, 128, 64, nullptr, nullptr);

    // 12. cosine similarity
    cosine_kernel<<<NTRAIN / 4, blk, 0, stream>>>(tfa, tga, ts, (float*)d_out);
}

// Round 8
// 1051.099 us; speedup vs baseline: 2.1184x; 1.0233x over previous
//
#include <hip/hip_runtime.h>
#include <hip/hip_bf16.h>

#define N_NODES 20000
#define E_EDGES 320000
#define NTRAIN  200000
#define KC_SPLITS 64

// ---------------------------------------------------------------------------
// f32 LDS-tiled GEMM, BM=64 BN=64, 4x4/thread (used for N=64 outputs)
// PRE: 0 none, 1 sigmoid, 2 +pos_emb[positions[row]] ; POST: 0 none, 1 leaky
// ---------------------------------------------------------------------------
template<int PRE, int POST>
__global__ __launch_bounds__(256) void gemm_f32(
    const float* __restrict__ A, const float* __restrict__ W,
    const float* __restrict__ bias, float* __restrict__ C,
    int M, int K, int Nn,
    const int* __restrict__ positions, const float* __restrict__ pos_emb)
{
    __shared__ float As[16][68];
    __shared__ float Bs[16][64];

    const int t  = threadIdx.x;
    const int m0 = blockIdx.x * 64;
    const int n0 = blockIdx.y * 64;

    const int kl  = t & 15;
    const int ml  = t >> 4;
    const int nl  = t & 63;
    const int kl2 = t >> 6;
    const int tc  = t & 15;
    const int tr  = t >> 4;

    float acc[4][4] = {};

    for (int k0 = 0; k0 < K; k0 += 16) {
        #pragma unroll
        for (int i = 0; i < 4; i++) {
            int row = m0 + ml + i * 16;
            float v = 0.f;
            if (row < M) {
                v = A[(size_t)row * K + k0 + kl];
                if (PRE == 1) v = 1.f / (1.f + expf(-v));
                if (PRE == 2) v += pos_emb[(size_t)positions[row] * K + k0 + kl];
            }
            As[kl][ml + i * 16] = v;
        }
        #pragma unroll
        for (int i = 0; i < 4; i++) {
            int kk = kl2 * 4 + i;
            Bs[kk][nl] = W[(size_t)(k0 + kk) * Nn + n0 + nl];
        }
        __syncthreads();
        #pragma unroll
        for (int kk = 0; kk < 16; kk++) {
            float4 ra = *reinterpret_cast<const float4*>(&As[kk][tr * 4]);
            float4 rb = *reinterpret_cast<const float4*>(&Bs[kk][tc * 4]);
            float am[4] = {ra.x, ra.y, ra.z, ra.w};
            float bn[4] = {rb.x, rb.y, rb.z, rb.w};
            #pragma unroll
            for (int i = 0; i < 4; i++)
                #pragma unroll
                for (int j = 0; j < 4; j++)
                    acc[i][j] += am[i] * bn[j];
        }
        __syncthreads();
    }

    #pragma unroll
    for (int i = 0; i < 4; i++) {
        int row = m0 + tr * 4 + i;
        if (row >= M) continue;
        #pragma unroll
        for (int j = 0; j < 4; j++) {
            int col = n0 + tc * 4 + j;
            float v = acc[i][j] + (bias ? bias[col] : 0.f);
            if (POST == 1) v = (v >= 0.f) ? v : 0.01f * v;
            C[(size_t)row * Nn + col] = v;
        }
    }
}

// ---------------------------------------------------------------------------
// f32 LDS-tiled GEMM, BM=64 BN=128, 4x8/thread. Bs swizzled (+4*(col>>5)) so
// the 16-group float4 reads are 2-way on banks (free) instead of 4-way.
// ---------------------------------------------------------------------------
template<int PRE, int POST>
__global__ __launch_bounds__(256) void gemm_f32_n128(
    const float* __restrict__ A, const float* __restrict__ W,
    const float* __restrict__ bias, float* __restrict__ C,
    int M, int K, int Nn,
    const int* __restrict__ positions, const float* __restrict__ pos_emb)
{
    __shared__ float As[16][68];
    __shared__ float Bs[16][144];   // phys col = n + 4*(n>>5)

    const int t  = threadIdx.x;
    const int m0 = blockIdx.x * 64;
    const int n0 = blockIdx.y * 128;

    const int kl = t & 15;    // A-load k
    const int ml = t >> 4;    // A-load m base
    const int nl = t & 127;   // B-load n
    const int kb = t >> 7;    // B-load k base

    const int tc = t & 15;    // col group (8 cols)
    const int tr = t >> 4;    // row group (4 rows)
    const int bPhys = tc * 8 + (tc >> 2) * 4;

    float acc[4][8] = {};

    for (int k0 = 0; k0 < K; k0 += 16) {
        #pragma unroll
        for (int i = 0; i < 4; i++) {
            int row = m0 + ml + i * 16;
            float v = 0.f;
            if (row < M) {
                v = A[(size_t)row * K + k0 + kl];
                if (PRE == 1) v = 1.f / (1.f + expf(-v));
                if (PRE == 2) v += pos_emb[(size_t)positions[row] * K + k0 + kl];
            }
            As[kl][ml + i * 16] = v;
        }
        {
            int pc = nl + (nl >> 5) * 4;
            #pragma unroll
            for (int i = 0; i < 8; i++) {
                int kk = kb + i * 2;
                Bs[kk][pc] = W[(size_t)(k0 + kk) * Nn + n0 + nl];
            }
        }
        __syncthreads();
        #pragma unroll
        for (int kk = 0; kk < 16; kk++) {
            float4 ra  = *reinterpret_cast<const float4*>(&As[kk][tr * 4]);
            float4 rb0 = *reinterpret_cast<const float4*>(&Bs[kk][bPhys]);
            float4 rb1 = *reinterpret_cast<const float4*>(&Bs[kk][bPhys + 4]);
            float am[4] = {ra.x, ra.y, ra.z, ra.w};
            float bn[8] = {rb0.x, rb0.y, rb0.z, rb0.w, rb1.x, rb1.y, rb1.z, rb1.w};
            #pragma unroll
            for (int i = 0; i < 4; i++)
                #pragma unroll
                for (int j = 0; j < 8; j++)
                    acc[i][j] += am[i] * bn[j];
        }
        __syncthreads();
    }

    #pragma unroll
    for (int i = 0; i < 4; i++) {
        int row = m0 + tr * 4 + i;
        if (row >= M) continue;
        float4 o0, o1;
        float* po0 = (float*)&o0;
        float* po1 = (float*)&o1;
        #pragma unroll
        for (int j = 0; j < 4; j++) {
            float v = acc[i][j] + (bias ? bias[n0 + tc * 8 + j] : 0.f);
            if (POST == 1) v = (v >= 0.f) ? v : 0.01f * v;
            po0[j] = v;
            float w = acc[i][j + 4] + (bias ? bias[n0 + tc * 8 + 4 + j] : 0.f);
            if (POST == 1) w = (w >= 0.f) ? w : 0.01f * w;
            po1[j] = w;
        }
        *reinterpret_cast<float4*>(&C[(size_t)row * Nn + n0 + tc * 8])     = o0;
        *reinterpret_cast<float4*>(&C[(size_t)row * Nn + n0 + tc * 8 + 4]) = o1;
    }
}

__global__ void zero_kernel(float* __restrict__ p, int n)
{
    int i = blockIdx.x * 256 + threadIdx.x;
    if (i < n) p[i] = 0.f;
}

// ---------------------------------------------------------------------------
// CSR build step 1: count[n] = indegree(n)  (count pre-zeroed)
// ---------------------------------------------------------------------------
__global__ void csr_count(const int* __restrict__ dst, int* __restrict__ count)
{
    int e = blockIdx.x * 256 + threadIdx.x;
    int stride = gridDim.x * 256;
    for (; e < E_EDGES; e += stride)
        atomicAdd(&count[dst[e]], 1);
}

// ---------------------------------------------------------------------------
// CSR build step 2: single-block exclusive scan of count -> rowptr, cursor.
// Also emits dinv[n] = rsqrt(1 + indegree) (the GCN degree normalizer).
// ---------------------------------------------------------------------------
__global__ __launch_bounds__(1024) void csr_scan(
    const int* __restrict__ count, int* __restrict__ rowptr,
    int* __restrict__ cursor, float* __restrict__ dinv)
{
    __shared__ int s[1024];
    const int t = threadIdx.x;
    int carry = 0;
    for (int base = 0; base < N_NODES; base += 1024) {
        int i = base + t;
        int v = (i < N_NODES) ? count[i] : 0;
        if (i < N_NODES) dinv[i] = rsqrtf(1.f + (float)v);
        s[t] = v;
        __syncthreads();
        for (int off = 1; off < 1024; off <<= 1) {
            int add = (t >= off) ? s[t - off] : 0;
            __syncthreads();
            s[t] += add;
            __syncthreads();
        }
        int incl  = s[t];
        int total = s[1023];
        if (i < N_NODES) {
            rowptr[i] = carry + incl - v;
            cursor[i] = carry + incl - v;
        }
        carry += total;
        __syncthreads();   // s reused next iteration
    }
    if (t == 0) rowptr[N_NODES] = carry;
}

// ---------------------------------------------------------------------------
// CSR build step 3: bucket edge sources by dst
// ---------------------------------------------------------------------------
__global__ void csr_fill(const int* __restrict__ src, const int* __restrict__ dst,
                         int* __restrict__ cursor, int* __restrict__ srcs)
{
    int e = blockIdx.x * 256 + threadIdx.x;
    int stride = gridDim.x * 256;
    for (; e < E_EDGES; e += stride) {
        int slot = atomicAdd(&cursor[dst[e]], 1);
        srcs[slot] = src[e];
    }
}

// ---------------------------------------------------------------------------
// GCN aggregation, gather-side (no float atomics):
// O[n] = sum_{s in in(n)} H[s]*dinv[s]*dinv[n] + H[n]*dinv[n]^2 + b
// ---------------------------------------------------------------------------
__global__ __launch_bounds__(256) void gcn_aggregate(
    const float* __restrict__ H1, const float* __restrict__ H2,
    const float* __restrict__ dinv,
    const int* __restrict__ rowptr, const int* __restrict__ srcs,
    const float* __restrict__ b1, const float* __restrict__ b2,
    float* __restrict__ O1, float* __restrict__ O2)
{
    const int n = blockIdx.x;
    const int f = threadIdx.x;
    const float dn = dinv[n];
    const size_t nidx = (size_t)n * 256 + f;

    float a1 = H1[nidx] * dn * dn + b1[f];
    float a2 = H2[nidx] * dn * dn + b2[f];

    const int e0 = rowptr[n];
    const int e1 = rowptr[n + 1];
    for (int e = e0; e < e1; e++) {
        int s = srcs[e];
        float c = dinv[s] * dn;
        size_t si = (size_t)s * 256 + f;
        a1 += H1[si] * c;
        a2 += H2[si] * c;
    }
    O1[nidx] = a1;
    O2[nidx] = a2;
}

// ---------------------------------------------------------------------------
// kc/vc stage 1 v2: (256 x 20000) @ (20000 x 128), split-K + c-split,
// NO atomics. grid = (4 c-tiles of 64, KC_SPLITS, 2 mats) = 512 blocks
// (2/CU -> staging latency overlaps across blocks; the old 256-block grid
// was exactly 1 block/CU with zero co-residency).
// Es staged transposed [nn][c]; inner reads are float4, 2-way on banks.
// per-split chunk = 320 (mult of 32 -> 16B-aligned loads, no tail tiles).
// ---------------------------------------------------------------------------
__global__ __launch_bounds__(256) void kcvc_kernel(
    const float* __restrict__ Ek, const float* __restrict__ Ev,
    const float* __restrict__ kin, const float* __restrict__ vin,
    float* __restrict__ partial)
{
    const float* E = blockIdx.z ? Ev  : Ek;
    const float* X = blockIdx.z ? vin : kin;

    const int c0 = blockIdx.x * 64;
    const int per = 320;
    const int nStart = blockIdx.y * per;
    const int nEnd   = min(nStart + per, N_NODES);

    __shared__ float Es[32][68];    // [nn][c_local], pad 64->68
    __shared__ float Xs[32][144];   // [nn][d phys], phys = d + 4*(d>>5)

    const int t  = threadIdx.x;
    const int tc = t & 15;          // c-quad: c_local = 4*tc .. +3
    const int td = t >> 4;          // d-group: d = 8*td .. +7
    const int xPhys = td * 8 + (td >> 2) * 4;

    float acc[4][8] = {};

    for (int nb = nStart; nb < nEnd; nb += 32) {
        // stage E transposed: 64 rows, 4 threads/row, 8 nn each (aligned f4)
        {
            int cl  = t >> 2;
            int nnb = (t & 3) * 8;
            const float* srcp = &E[(size_t)(c0 + cl) * N_NODES + nb + nnb];
            float4 v0 = *reinterpret_cast<const float4*>(&srcp[0]);
            float4 v1 = *reinterpret_cast<const float4*>(&srcp[4]);
            Es[nnb + 0][cl] = v0.x; Es[nnb + 1][cl] = v0.y;
            Es[nnb + 2][cl] = v0.z; Es[nnb + 3][cl] = v0.w;
            Es[nnb + 4][cl] = v1.x; Es[nnb + 5][cl] = v1.y;
            Es[nnb + 6][cl] = v1.z; Es[nnb + 7][cl] = v1.w;
        }
        // stage X: 32 nn x 128 d, coalesced float4
        {
            #pragma unroll
            for (int i = 0; i < 4; i++) {
                int g  = t + i * 256;
                int nn = g >> 5;
                int d0 = (g & 31) * 4;
                int pd = d0 + (d0 >> 5) * 4;
                float4 v = *reinterpret_cast<const float4*>(&X[(size_t)(nb + nn) * 128 + d0]);
                Xs[nn][pd + 0] = v.x; Xs[nn][pd + 1] = v.y;
                Xs[nn][pd + 2] = v.z; Xs[nn][pd + 3] = v.w;
            }
        }
        __syncthreads();

        #pragma unroll 2
        for (int nn = 0; nn < 32; nn++) {
            float4 e4 = *reinterpret_cast<const float4*>(&Es[nn][tc * 4]);
            float4 x0 = *reinterpret_cast<const float4*>(&Xs[nn][xPhys]);
            float4 x1 = *reinterpret_cast<const float4*>(&Xs[nn][xPhys + 4]);
            float ev[4] = {e4.x, e4.y, e4.z, e4.w};
            float xv[8] = {x0.x, x0.y, x0.z, x0.w, x1.x, x1.y, x1.z, x1.w};
            #pragma unroll
            for (int ci = 0; ci < 4; ci++)
                #pragma unroll
                for (int dj = 0; dj < 8; dj++)
                    acc[ci][dj] += ev[ci] * xv[dj];
        }
        __syncthreads();
    }

    // plain cached stores of this block's 64x128 tile into its split slice
    float* pb = partial + (size_t)(blockIdx.z * KC_SPLITS + blockIdx.y) * 32768;
    #pragma unroll
    for (int ci = 0; ci < 4; ci++) {
        int c = c0 + tc * 4 + ci;
        float4 v0 = {acc[ci][0], acc[ci][1], acc[ci][2], acc[ci][3]};
        float4 v1 = {acc[ci][4], acc[ci][5], acc[ci][6], acc[ci][7]};
        *reinterpret_cast<float4*>(&pb[(size_t)c * 128 + td * 8])     = v0;
        *reinterpret_cast<float4*>(&pb[(size_t)c * 128 + td * 8 + 4]) = v1;
    }
}

// ---------------------------------------------------------------------------
// kc/vc stage 2: out[mat][c][d] = sum_s partial[mat][s][c][d]
// ---------------------------------------------------------------------------
__global__ __launch_bounds__(256) void kcvc_reduce(
    const float* __restrict__ partial, float* __restrict__ out)
{
    int i4  = blockIdx.x * 256 + threadIdx.x;    // [0, 16384)
    int mat = i4 >> 13;                          // 8192 float4 per matrix
    int off = (i4 & 8191) * 4;
    const float* p = partial + (size_t)mat * KC_SPLITS * 32768 + off;
    float4 acc = {0.f, 0.f, 0.f, 0.f};
    #pragma unroll 8
    for (int s = 0; s < KC_SPLITS; s++) {
        float4 v = *reinterpret_cast<const float4*>(p + (size_t)s * 32768);
        acc.x += v.x; acc.y += v.y; acc.z += v.z; acc.w += v.w;
    }
    *reinterpret_cast<float4*>(out + (size_t)mat * 32768 + off) = acc;
}

// ---------------------------------------------------------------------------
// Fused attention v3: block = 256 threads = 16 nodes, grid 1250.
// Score phase register-tiled like a GEMM (it IS Q[16x16] @ Kc^T[16x256]):
//   thread (ng=t>>6, tc2=t&63) computes 4 nodes x 4 c with q in registers
//   (per-wave all lanes share the same 4 nodes -> q reads broadcast; kc_s
//   float4 reads sit at the 8-words/bank floor). 16 b128 reads per head
//   instead of 256 scalar reads.
// PV phase: vc_s stored [d][c] so both operands read as float4:
//   out[node][d=tn] += w_s[node][4i..] (bcast) * vc_s[tn][4i..].
// ---------------------------------------------------------------------------
__global__ __launch_bounds__(256) void attn_kernel(
    const float* __restrict__ q, const float* __restrict__ kc,
    const float* __restrict__ vc, float* __restrict__ outp)
{
    __shared__ float q_s[16][132];
    __shared__ float kc_s[16][260];   // [d][c]
    __shared__ float vc_s[16][260];   // [d][c]
    __shared__ float w_s[16][260];    // [node][c]

    const int t    = threadIdx.x;
    const int n0   = blockIdx.x * 16;
    const int ng   = t >> 6;          // wave id -> nodes 4ng..4ng+3
    const int tc2  = t & 63;          // c-quad: c = 4*tc2 .. +3
    const int node = t >> 4;          // PV mapping
    const int tn   = t & 15;

    // stage q once: 16 nodes x 128 floats, 8 per thread
    {
        const float* qp = q + (size_t)n0 * 128;
        #pragma unroll
        for (int i = 0; i < 2; i++) {
            int idx = t * 8 + i * 4;
            float4 v = *reinterpret_cast<const float4*>(&qp[idx]);
            *reinterpret_cast<float4*>(&q_s[idx >> 7][idx & 127]) = v;
        }
    }

    for (int h = 0; h < 8; h++) {
        __syncthreads();   // prev head's PV reads done before restage
        // stage kc_h and vc_h transposed [d][c] (thread t owns column c = t)
        {
            const float* kp = &kc[(size_t)t * 128 + h * 16];
            float4 a0 = *reinterpret_cast<const float4*>(kp);
            float4 a1 = *reinterpret_cast<const float4*>(kp + 4);
            float4 a2 = *reinterpret_cast<const float4*>(kp + 8);
            float4 a3 = *reinterpret_cast<const float4*>(kp + 12);
            kc_s[ 0][t] = a0.x; kc_s[ 1][t] = a0.y; kc_s[ 2][t] = a0.z; kc_s[ 3][t] = a0.w;
            kc_s[ 4][t] = a1.x; kc_s[ 5][t] = a1.y; kc_s[ 6][t] = a1.z; kc_s[ 7][t] = a1.w;
            kc_s[ 8][t] = a2.x; kc_s[ 9][t] = a2.y; kc_s[10][t] = a2.z; kc_s[11][t] = a2.w;
            kc_s[12][t] = a3.x; kc_s[13][t] = a3.y; kc_s[14][t] = a3.z; kc_s[15][t] = a3.w;
            const float* vp = &vc[(size_t)t * 128 + h * 16];
            float4 b0 = *reinterpret_cast<const float4*>(vp);
            float4 b1 = *reinterpret_cast<const float4*>(vp + 4);
            float4 b2 = *reinterpret_cast<const float4*>(vp + 8);
            float4 b3 = *reinterpret_cast<const float4*>(vp + 12);
            vc_s[ 0][t] = b0.x; vc_s[ 1][t] = b0.y; vc_s[ 2][t] = b0.z; vc_s[ 3][t] = b0.w;
            vc_s[ 4][t] = b1.x; vc_s[ 5][t] = b1.y; vc_s[ 6][t] = b1.z; vc_s[ 7][t] = b1.w;
            vc_s[ 8][t] = b2.x; vc_s[ 9][t] = b2.y; vc_s[10][t] = b2.z; vc_s[11][t] = b2.w;
            vc_s[12][t] = b3.x; vc_s[13][t] = b3.y; vc_s[14][t] = b3.z; vc_s[15][t] = b3.w;
        }
        __syncthreads();

        // ---- score phase: 4 nodes x 4 c per thread, q in registers ----
        float qreg[4][16];
        #pragma unroll
        for (int j = 0; j < 4; j++)
            #pragma unroll
            for (int dq = 0; dq < 4; dq++) {
                float4 qv = *reinterpret_cast<const float4*>(&q_s[4 * ng + j][h * 16 + 4 * dq]);
                qreg[j][4 * dq + 0] = qv.x; qreg[j][4 * dq + 1] = qv.y;
                qreg[j][4 * dq + 2] = qv.z; qreg[j][4 * dq + 3] = qv.w;
            }

        float sv[4][4] = {};
        #pragma unroll
        for (int d = 0; d < 16; d++) {
            float4 kv = *reinterpret_cast<const float4*>(&kc_s[d][4 * tc2]);
            float kvv[4] = {kv.x, kv.y, kv.z, kv.w};
            #pragma unroll
            for (int j = 0; j < 4; j++)
                #pragma unroll
                for (int i = 0; i < 4; i++)
                    sv[j][i] += qreg[j][d] * kvv[i];
        }

        float mx[4], sm[4];
        #pragma unroll
        for (int j = 0; j < 4; j++) {
            #pragma unroll
            for (int i = 0; i < 4; i++) sv[j][i] *= 0.25f;
            mx[j] = fmaxf(fmaxf(sv[j][0], sv[j][1]), fmaxf(sv[j][2], sv[j][3]));
        }
        #pragma unroll
        for (int off = 32; off > 0; off >>= 1)
            #pragma unroll
            for (int j = 0; j < 4; j++)
                mx[j] = fmaxf(mx[j], __shfl_xor(mx[j], off));
        #pragma unroll
        for (int j = 0; j < 4; j++) {
            sm[j] = 0.f;
            #pragma unroll
            for (int i = 0; i < 4; i++) {
                sv[j][i] = expf(sv[j][i] - mx[j]);
                sm[j] += sv[j][i];
            }
        }
        #pragma unroll
        for (int off = 32; off > 0; off >>= 1)
            #pragma unroll
            for (int j = 0; j < 4; j++)
                sm[j] += __shfl_xor(sm[j], off);
        #pragma unroll
        for (int j = 0; j < 4; j++) {
            float inv = 1.0f / sm[j];
            float4 wv = {sv[j][0] * inv, sv[j][1] * inv, sv[j][2] * inv, sv[j][3] * inv};
            *reinterpret_cast<float4*>(&w_s[4 * ng + j][4 * tc2]) = wv;
        }
        __syncthreads();

        // ---- PV phase: out[node][h*16+tn] = sum_c w[c] * vc_s[tn][c] ----
        float a0 = 0.f, a1 = 0.f, a2 = 0.f, a3 = 0.f;
        #pragma unroll 8
        for (int i = 0; i < 64; i++) {
            float4 w4 = *reinterpret_cast<const float4*>(&w_s[node][4 * i]);
            float4 v4 = *reinterpret_cast<const float4*>(&vc_s[tn][4 * i]);
            a0 += w4.x * v4.x;
            a1 += w4.y * v4.y;
            a2 += w4.z * v4.z;
            a3 += w4.w * v4.w;
        }
        outp[(size_t)(n0 + node) * 128 + h * 16 + tn] = (a0 + a1) + (a2 + a3);
    }
}

// ---------------------------------------------------------------------------
// Cosine similarity: one wave per pair, 64 lanes = 64 features
// ---------------------------------------------------------------------------
__global__ __launch_bounds__(256) void cosine_kernel(
    const float* __restrict__ tfa, const float* __restrict__ tga,
    const int* __restrict__ ts, float* __restrict__ out)
{
    const int w    = threadIdx.x >> 6;
    const int lane = threadIdx.x & 63;
    const int t    = blockIdx.x * 4 + w;
    if (t >= NTRAIN) return;

    int i = ts[2 * t];
    int j = ts[2 * t + 1];
    float a = tfa[(size_t)i * 64 + lane];
    float b = tga[(size_t)j * 64 + lane];
    float da = a * b, na = a * a, nb = b * b;
    #pragma unroll
    for (int off = 32; off > 0; off >>= 1) {
        da += __shfl_xor(da, off);
        na += __shfl_xor(na, off);
        nb += __shfl_xor(nb, off);
    }
    if (lane == 0)
        out[t] = da / fmaxf(sqrtf(na) * sqrtf(nb), 1e-8f);
}

// ---------------------------------------------------------------------------
extern "C" void kernel_launch(void* const* d_in, const int* in_sizes, int n_in,
                              void* d_out, int out_size, void* d_ws, size_t ws_size,
                              hipStream_t stream)
{
    const int*   ts    = (const int*)  d_in[1];
    const float* X     = (const float*)d_in[2];
    const int*   adj   = (const int*)  d_in[3];
    const int*   pos   = (const int*)  d_in[4];
    const float* gcn_W = (const float*)d_in[5];
    const float* gcn_b = (const float*)d_in[6];
    const float* gA2_W = (const float*)d_in[7];
    const float* gA2_b = (const float*)d_in[8];
    const float* lin_W = (const float*)d_in[9];
    const float* lin_b = (const float*)d_in[10];
    const float* tf_W  = (const float*)d_in[11];
    const float* tf_b  = (const float*)d_in[12];
    const float* tg_W  = (const float*)d_in[13];
    const float* tg_b  = (const float*)d_in[14];
    const float* Wq    = (const float*)d_in[15];
    const float* bq    = (const float*)d_in[16];
    const float* Wk    = (const float*)d_in[17];
    const float* bk    = (const float*)d_in[18];
    const float* Wv    = (const float*)d_in[19];
    const float* bv    = (const float*)d_in[20];
    const float* Wo    = (const float*)d_in[21];
    const float* bo    = (const float*)d_in[22];
    const float* Ek    = (const float*)d_in[23];
    const float* Ev    = (const float*)d_in[24];
    const float* pemb  = (const float*)d_in[25];
    const float* tfaW  = (const float*)d_in[26];
    const float* tfab  = (const float*)d_in[27];
    const float* tgaW  = (const float*)d_in[28];
    const float* tgab  = (const float*)d_in[29];

    const int* src = adj;
    const int* dst = adj + E_EDGES;

    float* ws  = (float*)d_ws;
    float* H1  = ws;                 // 20000*256
    float* H2  = H1 + 5120000;
    float* O1  = H2 + 5120000;
    float* O2  = O1 + 5120000;
    float* dinv = O2 + 5120000;      // 20000
    float* kc  = dinv + 20000;       // 256*128
    float* vc  = kc + 32768;         // 256*128
    int*   count  = (int*)(vc + 32768);     // 20000
    int*   rowptr = count + 20000;          // 20001
    int*   cursor = rowptr + 20001;         // 20000
    int*   srcs   = cursor + 20000;         // 320000
    // aliases over dead buffers:
    float* xg   = H1;
    float* tfe  = H1 + 2560000;
    float* tge  = H2;
    float* qb   = H2 + 2560000;
    float* kb   = O1;
    float* vb   = O1 + 2560000;
    float* attn = O2;
    float* xf   = O2 + 2560000;
    float* tfa  = H1;
    float* tga  = H1 + 1280000;
    // kcvc split-K partials: 2*KC_SPLITS*32768 = 4.19M floats, overlays H1
    float* partial = H1;

    dim3 blk(256);
    const int MB = (N_NODES + 63) / 64;   // 313

    // 1-2. H1 = X @ gcn_W ; H2 = X @ gcnA2_W
    gemm_f32_n128<0,0><<<dim3(MB,2), blk, 0, stream>>>(X, gcn_W, nullptr, H1, N_NODES, 512, 256, nullptr, nullptr);
    gemm_f32_n128<0,0><<<dim3(MB,2), blk, 0, stream>>>(X, gA2_W, nullptr, H2, N_NODES, 512, 256, nullptr, nullptr);

    // 3. CSR build (also yields dinv)
    zero_kernel<<<(20000 + 255) / 256, blk, 0, stream>>>((float*)count, 20000);
    csr_count<<<1250, blk, 0, stream>>>(dst, count);
    csr_scan<<<1, 1024, 0, stream>>>(count, rowptr, cursor, dinv);
    csr_fill<<<1250, blk, 0, stream>>>(src, dst, cursor, srcs);

    // 4. gather-side aggregation, fused self-term + bias (both GCNs)
    gcn_aggregate<<<N_NODES, blk, 0, stream>>>(H1, H2, dinv, rowptr, srcs,
                                               gcn_b, gA2_b, O1, O2);

    // 5-6. projections to HIDDEN
    gemm_f32_n128<1,1><<<dim3(MB,1), blk, 0, stream>>>(O1, lin_W, lin_b, xg, N_NODES, 256, 128, nullptr, nullptr);
    gemm_f32_n128<0,1><<<dim3(MB,1), blk, 0, stream>>>(O2, tf_W, tf_b, tfe, N_NODES, 256, 128, nullptr, nullptr);
    gemm_f32_n128<0,1><<<dim3(MB,1), blk, 0, stream>>>(O2, tg_W, tg_b, tge, N_NODES, 256, 128, nullptr, nullptr);

    // 7. q / k / v
    gemm_f32_n128<2,0><<<dim3(MB,1), blk, 0, stream>>>(xg,  Wq, bq, qb, N_NODES, 128, 128, pos, pemb);
    gemm_f32_n128<2,0><<<dim3(MB,1), blk, 0, stream>>>(tfe, Wk, bk, kb, N_NODES, 128, 128, pos, pemb);
    gemm_f32_n128<0,0><<<dim3(MB,1), blk, 0, stream>>>(tge, Wv, bv, vb, N_NODES, 128, 128, nullptr, nullptr);

    // 8. kc/vc: split-K + c-split partials (no atomics) + reduce
    kcvc_kernel<<<dim3(4, KC_SPLITS, 2), blk, 0, stream>>>(Ek, Ev, kb, vb, partial);
    kcvc_reduce<<<64, blk, 0, stream>>>(partial, kc);

    // 9. attention (16 nodes/block, 1250 blocks)
    attn_kernel<<<1250, blk, 0, stream>>>(qb, kc, vc, attn);

    // 10. x_f = attn @ Wo + bo
    gemm_f32_n128<0,0><<<dim3(MB,1), blk, 0, stream>>>(attn, Wo, bo, xf, N_NODES, 128, 128, nullptr, nullptr);

    // 11. tfa / tga
    gemm_f32<0,1><<<dim3(MB,1), blk, 0, stream>>>(xf, tfaW, tfab, tfa, N_NODES, 128, 64, nullptr, nullptr);
    gemm_f32<0,1><<<dim3(MB,1), blk, 0, stream>>>(xf, tgaW, tgab, tga, N_NODES, 128, 64, nullptr, nullptr);

    // 12. cosine similarity
    cosine_kernel<<<NTRAIN / 4, blk, 0, stream>>>(tfa, tga, ts, (float*)d_out);
}